// Round 1
// baseline (532.032 us; speedup 1.0000x reference)
//
#include <hip/hip_runtime.h>
#include <math.h>

// Problem constants (verified against reference setup_inputs)
#define NODES    50000
#define IN_CH    256
#define HID      128
#define HEADS    3
#define HC       64
#define OC       (HEADS*HC)   // 192
#define NEG_SLOPE 0.2f

// ---------------- CSR build ----------------

__global__ __launch_bounds__(256) void k_hist(const int* __restrict__ dst, int E, int* __restrict__ cnt) {
    int e = blockIdx.x * 256 + threadIdx.x;
    if (e < E) atomicAdd(&cnt[dst[e]], 1);
}

// Single-block exclusive scan of cnt[0..n) -> off[0..n], plus dinv = rsqrt(cnt+1)
__global__ __launch_bounds__(1024) void k_scan(const int* __restrict__ cnt, int* __restrict__ off,
                                               float* __restrict__ dinv, int n) {
    __shared__ int wsums[16];
    __shared__ int sh_base;
    __shared__ int sh_total;
    int tid = threadIdx.x, lane = tid & 63, wid = tid >> 6;
    if (tid == 0) sh_base = 0;
    __syncthreads();
    int nchunks = (n + 1023) / 1024;
    for (int c = 0; c < nchunks; c++) {
        int i = c * 1024 + tid;
        int v = (i < n) ? cnt[i] : 0;
        int incl = v;
        #pragma unroll
        for (int d = 1; d < 64; d <<= 1) {
            int t = __shfl_up(incl, d, 64);
            if (lane >= d) incl += t;
        }
        if (lane == 63) wsums[wid] = incl;
        __syncthreads();
        if (tid == 0) {
            int run = 0;
            for (int j = 0; j < 16; j++) { int t = wsums[j]; wsums[j] = run; run += t; }
            sh_total = run;
        }
        __syncthreads();
        int excl = sh_base + wsums[wid] + incl - v;
        if (i < n) {
            off[i] = excl;
            dinv[i] = rsqrtf((float)(v + 1));   // +1 for self loop
        }
        __syncthreads();
        if (tid == 0) sh_base += sh_total;
        __syncthreads();
    }
    if (tid == 0) off[n] = sh_base;
}

__global__ __launch_bounds__(256) void k_fill(const int* __restrict__ src, const int* __restrict__ dst, int E,
                                              const int* __restrict__ off, int* __restrict__ fill,
                                              int* __restrict__ csr) {
    int e = blockIdx.x * 256 + threadIdx.x;
    if (e < E) {
        int d = dst[e];
        int p = off[d] + atomicAdd(&fill[d], 1);
        csr[p] = src[e];
    }
}

// ---------------- GEMM1: xw = x @ W1   [N,256]x[256,128] ----------------
// 128x128 block tile, 16x16 threads, 8x8 micro-tile, BK=16.
__global__ __launch_bounds__(256) void k_gemm1(const float* __restrict__ x, const float* __restrict__ W1,
                                               float* __restrict__ xw, int n) {
    __shared__ float As[16][128];  // [kk][row]
    __shared__ float Bs[16][128];  // [kk][col]
    int tid = threadIdx.x;
    int tx = tid & 15, ty = tid >> 4;
    int row0 = blockIdx.x * 128;

    float acc[8][8];
    #pragma unroll
    for (int i = 0; i < 8; i++)
        #pragma unroll
        for (int j = 0; j < 8; j++) acc[i][j] = 0.f;

    int lr = tid >> 1;              // row for x load
    int lk = (tid & 1) * 8;         // k offset for x load
    int wk = tid >> 4;              // k row for W load
    int wj = (tid & 15) * 8;        // col for W load

    for (int kc = 0; kc < IN_CH; kc += 16) {
        int grow = row0 + lr;
        float4 v0, v1;
        if (grow < n) {
            const float* p = x + (size_t)grow * IN_CH + kc + lk;
            v0 = *(const float4*)(p);
            v1 = *(const float4*)(p + 4);
        } else {
            v0 = make_float4(0.f, 0.f, 0.f, 0.f);
            v1 = v0;
        }
        As[lk + 0][lr] = v0.x; As[lk + 1][lr] = v0.y; As[lk + 2][lr] = v0.z; As[lk + 3][lr] = v0.w;
        As[lk + 4][lr] = v1.x; As[lk + 5][lr] = v1.y; As[lk + 6][lr] = v1.z; As[lk + 7][lr] = v1.w;

        const float* wp = W1 + (size_t)(kc + wk) * HID + wj;
        float4 w0 = *(const float4*)(wp);
        float4 w1 = *(const float4*)(wp + 4);
        *(float4*)&Bs[wk][wj] = w0;
        *(float4*)&Bs[wk][wj + 4] = w1;
        __syncthreads();

        #pragma unroll
        for (int kk = 0; kk < 16; kk++) {
            float a[8], b[8];
            *(float4*)&a[0] = *(const float4*)&As[kk][ty * 8];
            *(float4*)&a[4] = *(const float4*)&As[kk][ty * 8 + 4];
            *(float4*)&b[0] = *(const float4*)&Bs[kk][tx * 8];
            *(float4*)&b[4] = *(const float4*)&Bs[kk][tx * 8 + 4];
            #pragma unroll
            for (int i = 0; i < 8; i++)
                #pragma unroll
                for (int j = 0; j < 8; j++) acc[i][j] += a[i] * b[j];
        }
        __syncthreads();
    }

    #pragma unroll
    for (int i = 0; i < 8; i++) {
        int row = row0 + ty * 8 + i;
        if (row < n) {
            float* po = xw + (size_t)row * HID + tx * 8;
            *(float4*)(po)     = make_float4(acc[i][0], acc[i][1], acc[i][2], acc[i][3]);
            *(float4*)(po + 4) = make_float4(acc[i][4], acc[i][5], acc[i][6], acc[i][7]);
        }
    }
}

// ---------------- GCN aggregate: one wave per dst node ----------------
__global__ __launch_bounds__(256) void k_gcn(const float* __restrict__ xw, const int* __restrict__ csr,
                                             const int* __restrict__ off, const float* __restrict__ dinv,
                                             const float* __restrict__ b1, float* __restrict__ h, int n) {
    int w = (blockIdx.x * 256 + threadIdx.x) >> 6;
    int lane = threadIdx.x & 63;
    if (w >= n) return;
    float di = dinv[w];
    float acc0 = 0.f, acc1 = 0.f;
    int beg = off[w], end = off[w + 1];
    for (int i = beg; i < end; i++) {
        int s = csr[i];
        float nrm = dinv[s] * di;
        const float* p = xw + (size_t)s * HID;
        acc0 += p[lane] * nrm;
        acc1 += p[lane + 64] * nrm;
    }
    const float* ps = xw + (size_t)w * HID;
    float sl = di * di;  // self loop norm
    acc0 += ps[lane] * sl;
    acc1 += ps[lane + 64] * sl;
    h[(size_t)w * HID + lane]      = fmaxf(acc0 + b1[lane], 0.f);
    h[(size_t)w * HID + lane + 64] = fmaxf(acc1 + b1[lane + 64], 0.f);
}

// ---------------- GEMM2: h2 = h @ W2   [N,128]x[128,192] ----------------
// 128x64 block tile (blockIdx.y = col tile 0..2), 16x16 threads, 8x4 micro-tile.
__global__ __launch_bounds__(256) void k_gemm2(const float* __restrict__ h, const float* __restrict__ W2,
                                               float* __restrict__ h2, int n) {
    __shared__ float As[16][128];  // [kk][row]
    __shared__ float Bs[16][64];   // [kk][col]
    int tid = threadIdx.x;
    int tx = tid & 15, ty = tid >> 4;
    int row0 = blockIdx.x * 128;
    int col0 = blockIdx.y * 64;

    float acc[8][4];
    #pragma unroll
    for (int i = 0; i < 8; i++)
        #pragma unroll
        for (int j = 0; j < 4; j++) acc[i][j] = 0.f;

    int lr = tid >> 1;
    int lk = (tid & 1) * 8;
    int wk = tid >> 4;
    int wj = (tid & 15) * 4;

    for (int kc = 0; kc < HID; kc += 16) {
        int grow = row0 + lr;
        float4 v0, v1;
        if (grow < n) {
            const float* p = h + (size_t)grow * HID + kc + lk;
            v0 = *(const float4*)(p);
            v1 = *(const float4*)(p + 4);
        } else {
            v0 = make_float4(0.f, 0.f, 0.f, 0.f);
            v1 = v0;
        }
        As[lk + 0][lr] = v0.x; As[lk + 1][lr] = v0.y; As[lk + 2][lr] = v0.z; As[lk + 3][lr] = v0.w;
        As[lk + 4][lr] = v1.x; As[lk + 5][lr] = v1.y; As[lk + 6][lr] = v1.z; As[lk + 7][lr] = v1.w;

        float4 w0 = *(const float4*)(W2 + (size_t)(kc + wk) * OC + col0 + wj);
        *(float4*)&Bs[wk][wj] = w0;
        __syncthreads();

        #pragma unroll
        for (int kk = 0; kk < 16; kk++) {
            float a[8], b[4];
            *(float4*)&a[0] = *(const float4*)&As[kk][ty * 8];
            *(float4*)&a[4] = *(const float4*)&As[kk][ty * 8 + 4];
            *(float4*)&b[0] = *(const float4*)&Bs[kk][tx * 4];
            #pragma unroll
            for (int i = 0; i < 8; i++)
                #pragma unroll
                for (int j = 0; j < 4; j++) acc[i][j] += a[i] * b[j];
        }
        __syncthreads();
    }

    #pragma unroll
    for (int i = 0; i < 8; i++) {
        int row = row0 + ty * 8 + i;
        if (row < n) {
            float* po = h2 + (size_t)row * OC + col0 + tx * 4;
            *(float4*)(po) = make_float4(acc[i][0], acc[i][1], acc[i][2], acc[i][3]);
        }
    }
}

// ---------------- attention scores: a_s/a_d [N,3] ----------------
__global__ __launch_bounds__(256) void k_att(const float* __restrict__ h2, const float* __restrict__ att_s,
                                             const float* __restrict__ att_d, float* __restrict__ a_s,
                                             float* __restrict__ a_d, int n) {
    int w = (blockIdx.x * 256 + threadIdx.x) >> 6;
    int lane = threadIdx.x & 63;
    if (w >= n) return;
    #pragma unroll
    for (int hd = 0; hd < HEADS; hd++) {
        float hv = h2[(size_t)w * OC + hd * HC + lane];
        float vs = hv * att_s[hd * HC + lane];
        float vd = hv * att_d[hd * HC + lane];
        #pragma unroll
        for (int o = 32; o > 0; o >>= 1) {
            vs += __shfl_xor(vs, o, 64);
            vd += __shfl_xor(vd, o, 64);
        }
        if (lane == 0) {
            a_s[w * HEADS + hd] = vs;
            a_d[w * HEADS + hd] = vd;
        }
    }
}

__device__ __forceinline__ float lrelu(float v) { return v > 0.f ? v : NEG_SLOPE * v; }

// ---------------- GAT aggregate: one wave per dst node, 2-pass softmax ----------------
__global__ __launch_bounds__(256) void k_gat(const float* __restrict__ h2, const int* __restrict__ csr,
                                             const int* __restrict__ off, const float* __restrict__ a_s,
                                             const float* __restrict__ a_d, const float* __restrict__ b2,
                                             float* __restrict__ out, int n) {
    int w = (blockIdx.x * 256 + threadIdx.x) >> 6;
    int lane = threadIdx.x & 63;
    if (w >= n) return;

    float add_[HEADS], eself[HEADS], m[HEADS];
    #pragma unroll
    for (int hd = 0; hd < HEADS; hd++) {
        add_[hd] = a_d[w * HEADS + hd];
        eself[hd] = lrelu(a_s[w * HEADS + hd] + add_[hd]);
        m[hd] = eself[hd];
    }
    int beg = off[w], end = off[w + 1];

    // pass 1: per-head max
    for (int i = beg; i < end; i++) {
        int s = csr[i];
        #pragma unroll
        for (int hd = 0; hd < HEADS; hd++) {
            float e = lrelu(a_s[s * HEADS + hd] + add_[hd]);
            m[hd] = fmaxf(m[hd], e);
        }
    }

    // pass 2: exp-sum + weighted accumulate
    float ssum[HEADS], acc[HEADS];
    const float* pself = h2 + (size_t)w * OC;
    #pragma unroll
    for (int hd = 0; hd < HEADS; hd++) {
        float ws = __expf(eself[hd] - m[hd]);
        ssum[hd] = ws;
        acc[hd] = ws * pself[hd * HC + lane];
    }
    for (int i = beg; i < end; i++) {
        int s = csr[i];
        const float* p = h2 + (size_t)s * OC;
        #pragma unroll
        for (int hd = 0; hd < HEADS; hd++) {
            float e = lrelu(a_s[s * HEADS + hd] + add_[hd]);
            float we = __expf(e - m[hd]);
            ssum[hd] += we;
            acc[hd] += we * p[hd * HC + lane];
        }
    }
    #pragma unroll
    for (int hd = 0; hd < HEADS; hd++) {
        float o = acc[hd] / ssum[hd] + b2[hd * HC + lane];
        out[(size_t)w * OC + hd * HC + lane] = fmaxf(o, 0.f);
    }
}

// ---------------- launcher ----------------
extern "C" void kernel_launch(void* const* d_in, const int* in_sizes, int n_in,
                              void* d_out, int out_size, void* d_ws, size_t ws_size,
                              hipStream_t stream) {
    const float* x        = (const float*)d_in[0];
    const int*   ei       = (const int*)d_in[1];
    const float* W1       = (const float*)d_in[2];
    const float* b1       = (const float*)d_in[3];
    const float* W2       = (const float*)d_in[4];
    const float* att_src  = (const float*)d_in[5];
    const float* att_dst  = (const float*)d_in[6];
    const float* b2       = (const float*)d_in[7];
    float* out = (float*)d_out;

    const int n = in_sizes[0] / IN_CH;     // 50000
    const int E = in_sizes[1] / 2;         // 800000
    const int* src = ei;
    const int* dst = ei + E;

    // workspace layout (bytes), all offsets 256-aligned
    char* ws = (char*)d_ws;
    int*   cnt  = (int*)(ws + 0);                   // 50000 int
    int*   fill = (int*)(ws + 200192);              // 50000 int
    int*   off  = (int*)(ws + 400384);              // 50001 int
    float* dinv = (float*)(ws + 600576);            // 50000 f
    int*   csr  = (int*)(ws + 800768);              // 800000 int
    float* xw   = (float*)(ws + 4000768);           // 50000*128 f
    float* h    = (float*)(ws + 29600768);          // 50000*128 f
    float* h2   = (float*)(ws + 55200768);          // 50000*192 f
    float* a_s  = (float*)(ws + 93600768);          // 50000*3 f
    float* a_d  = (float*)(ws + 94200832);          // 50000*3 f
    // total ~94.8 MB

    // zero cnt + fill (contiguous-ish: two ranges; one memset covers both regions)
    hipMemsetAsync(ws, 0, 400384, stream);

    int egrid = (E + 255) / 256;
    k_hist<<<egrid, 256, 0, stream>>>(dst, E, cnt);
    k_scan<<<1, 1024, 0, stream>>>(cnt, off, dinv, n);
    k_fill<<<egrid, 256, 0, stream>>>(src, dst, E, off, fill, csr);

    int g1 = (n + 127) / 128;
    k_gemm1<<<g1, 256, 0, stream>>>(x, W1, xw, n);

    int ngrid = (n + 3) / 4;   // 4 waves per block
    k_gcn<<<ngrid, 256, 0, stream>>>(xw, csr, off, dinv, b1, h, n);

    dim3 g2((n + 127) / 128, 3);
    k_gemm2<<<g2, 256, 0, stream>>>(h, W2, h2, n);

    k_att<<<ngrid, 256, 0, stream>>>(h2, att_src, att_dst, a_s, a_d, n);
    k_gat<<<ngrid, 256, 0, stream>>>(h2, csr, off, a_s, a_d, b2, out, n);
}

// Round 2
// 408.988 us; speedup vs baseline: 1.3008x; 1.3008x over previous
//
#include <hip/hip_runtime.h>
#include <math.h>

// Problem constants (verified against reference setup_inputs)
#define NODES    50000
#define IN_CH    256
#define HID      128
#define HEADS    3
#define HC       64
#define OC       (HEADS*HC)   // 192
#define NEG_SLOPE 0.2f

// ---------------- CSR build ----------------

__global__ __launch_bounds__(256) void k_hist(const int* __restrict__ dst, int E, int* __restrict__ cnt) {
    int e = blockIdx.x * 256 + threadIdx.x;
    if (e < E) atomicAdd(&cnt[dst[e]], 1);
}

// Single-block exclusive scan of cnt[0..n) -> off[0..n], plus dinv = rsqrt(cnt+1)
__global__ __launch_bounds__(1024) void k_scan(const int* __restrict__ cnt, int* __restrict__ off,
                                               float* __restrict__ dinv, int n) {
    __shared__ int wsums[16];
    __shared__ int sh_base;
    __shared__ int sh_total;
    int tid = threadIdx.x, lane = tid & 63, wid = tid >> 6;
    if (tid == 0) sh_base = 0;
    __syncthreads();
    int nchunks = (n + 1023) / 1024;
    for (int c = 0; c < nchunks; c++) {
        int i = c * 1024 + tid;
        int v = (i < n) ? cnt[i] : 0;
        int incl = v;
        #pragma unroll
        for (int d = 1; d < 64; d <<= 1) {
            int t = __shfl_up(incl, d, 64);
            if (lane >= d) incl += t;
        }
        if (lane == 63) wsums[wid] = incl;
        __syncthreads();
        if (tid == 0) {
            int run = 0;
            for (int j = 0; j < 16; j++) { int t = wsums[j]; wsums[j] = run; run += t; }
            sh_total = run;
        }
        __syncthreads();
        int excl = sh_base + wsums[wid] + incl - v;
        if (i < n) {
            off[i] = excl;
            dinv[i] = rsqrtf((float)(v + 1));   // +1 for self loop
        }
        __syncthreads();
        if (tid == 0) sh_base += sh_total;
        __syncthreads();
    }
    if (tid == 0) off[n] = sh_base;
}

__global__ __launch_bounds__(256) void k_fill(const int* __restrict__ src, const int* __restrict__ dst, int E,
                                              const int* __restrict__ off, int* __restrict__ fill,
                                              int* __restrict__ csr) {
    int e = blockIdx.x * 256 + threadIdx.x;
    if (e < E) {
        int d = dst[e];
        int p = off[d] + atomicAdd(&fill[d], 1);
        csr[p] = src[e];
    }
}

// ---------------- GEMM1: xw = dinv[row] * (x @ W1)   [N,256]x[256,128] ----------------
// 128x128 block tile, 16x16 threads, 8x8 micro-tile, BK=16.
// dinv pre-scaling folded into the epilogue so k_gcn needs no per-edge dinv gather.
__global__ __launch_bounds__(256) void k_gemm1(const float* __restrict__ x, const float* __restrict__ W1,
                                               const float* __restrict__ dinv,
                                               float* __restrict__ xw, int n) {
    __shared__ float As[16][128];  // [kk][row]
    __shared__ float Bs[16][128];  // [kk][col]
    int tid = threadIdx.x;
    int tx = tid & 15, ty = tid >> 4;
    int row0 = blockIdx.x * 128;

    float acc[8][8];
    #pragma unroll
    for (int i = 0; i < 8; i++)
        #pragma unroll
        for (int j = 0; j < 8; j++) acc[i][j] = 0.f;

    int lr = tid >> 1;              // row for x load
    int lk = (tid & 1) * 8;         // k offset for x load
    int wk = tid >> 4;              // k row for W load
    int wj = (tid & 15) * 8;        // col for W load

    for (int kc = 0; kc < IN_CH; kc += 16) {
        int grow = row0 + lr;
        float4 v0, v1;
        if (grow < n) {
            const float* p = x + (size_t)grow * IN_CH + kc + lk;
            v0 = *(const float4*)(p);
            v1 = *(const float4*)(p + 4);
        } else {
            v0 = make_float4(0.f, 0.f, 0.f, 0.f);
            v1 = v0;
        }
        As[lk + 0][lr] = v0.x; As[lk + 1][lr] = v0.y; As[lk + 2][lr] = v0.z; As[lk + 3][lr] = v0.w;
        As[lk + 4][lr] = v1.x; As[lk + 5][lr] = v1.y; As[lk + 6][lr] = v1.z; As[lk + 7][lr] = v1.w;

        const float* wp = W1 + (size_t)(kc + wk) * HID + wj;
        float4 w0 = *(const float4*)(wp);
        float4 w1 = *(const float4*)(wp + 4);
        *(float4*)&Bs[wk][wj] = w0;
        *(float4*)&Bs[wk][wj + 4] = w1;
        __syncthreads();

        #pragma unroll
        for (int kk = 0; kk < 16; kk++) {
            float a[8], b[8];
            *(float4*)&a[0] = *(const float4*)&As[kk][ty * 8];
            *(float4*)&a[4] = *(const float4*)&As[kk][ty * 8 + 4];
            *(float4*)&b[0] = *(const float4*)&Bs[kk][tx * 8];
            *(float4*)&b[4] = *(const float4*)&Bs[kk][tx * 8 + 4];
            #pragma unroll
            for (int i = 0; i < 8; i++)
                #pragma unroll
                for (int j = 0; j < 8; j++) acc[i][j] += a[i] * b[j];
        }
        __syncthreads();
    }

    #pragma unroll
    for (int i = 0; i < 8; i++) {
        int row = row0 + ty * 8 + i;
        if (row < n) {
            float sc = dinv[row];
            float* po = xw + (size_t)row * HID + tx * 8;
            *(float4*)(po)     = make_float4(sc*acc[i][0], sc*acc[i][1], sc*acc[i][2], sc*acc[i][3]);
            *(float4*)(po + 4) = make_float4(sc*acc[i][4], sc*acc[i][5], sc*acc[i][6], sc*acc[i][7]);
        }
    }
}

// ---------------- GCN aggregate: one wave per dst node, float2 lanes, unroll-4 ----------------
// xw rows are pre-scaled by dinv[row]; out = relu(dinv[w]*(sum_src xw'[s] + xw'[w]) + b1)
__global__ __launch_bounds__(256) void k_gcn(const float* __restrict__ xw, const int* __restrict__ csr,
                                             const int* __restrict__ off, const float* __restrict__ dinv,
                                             const float* __restrict__ b1, float* __restrict__ h, int n) {
    int w = (blockIdx.x * 256 + threadIdx.x) >> 6;
    int lane = threadIdx.x & 63;
    if (w >= n) return;
    float di = dinv[w];
    int c2 = lane * 2;
    float2 acc = *(const float2*)(xw + (size_t)w * HID + c2);   // self term (pre-scaled)
    int beg = off[w], end = off[w + 1];
    int i = beg;
    for (; i + 4 <= end; i += 4) {
        int sA = csr[i], sB = csr[i + 1], sC = csr[i + 2], sD = csr[i + 3];
        float2 vA = *(const float2*)(xw + (size_t)sA * HID + c2);
        float2 vB = *(const float2*)(xw + (size_t)sB * HID + c2);
        float2 vC = *(const float2*)(xw + (size_t)sC * HID + c2);
        float2 vD = *(const float2*)(xw + (size_t)sD * HID + c2);
        acc.x += vA.x; acc.y += vA.y;
        acc.x += vB.x; acc.y += vB.y;
        acc.x += vC.x; acc.y += vC.y;
        acc.x += vD.x; acc.y += vD.y;
    }
    for (; i < end; i++) {
        int s = csr[i];
        float2 v = *(const float2*)(xw + (size_t)s * HID + c2);
        acc.x += v.x; acc.y += v.y;
    }
    float2 bb = *(const float2*)(b1 + c2);
    float2 o;
    o.x = fmaxf(fmaf(di, acc.x, bb.x), 0.f);
    o.y = fmaxf(fmaf(di, acc.y, bb.y), 0.f);
    *(float2*)(h + (size_t)w * HID + c2) = o;
}

// ---------------- GEMM2: h2 = h @ W2   [N,128]x[128,192] ----------------
__global__ __launch_bounds__(256) void k_gemm2(const float* __restrict__ h, const float* __restrict__ W2,
                                               float* __restrict__ h2, int n) {
    __shared__ float As[16][128];  // [kk][row]
    __shared__ float Bs[16][64];   // [kk][col]
    int tid = threadIdx.x;
    int tx = tid & 15, ty = tid >> 4;
    int row0 = blockIdx.x * 128;
    int col0 = blockIdx.y * 64;

    float acc[8][4];
    #pragma unroll
    for (int i = 0; i < 8; i++)
        #pragma unroll
        for (int j = 0; j < 4; j++) acc[i][j] = 0.f;

    int lr = tid >> 1;
    int lk = (tid & 1) * 8;
    int wk = tid >> 4;
    int wj = (tid & 15) * 4;

    for (int kc = 0; kc < HID; kc += 16) {
        int grow = row0 + lr;
        float4 v0, v1;
        if (grow < n) {
            const float* p = h + (size_t)grow * HID + kc + lk;
            v0 = *(const float4*)(p);
            v1 = *(const float4*)(p + 4);
        } else {
            v0 = make_float4(0.f, 0.f, 0.f, 0.f);
            v1 = v0;
        }
        As[lk + 0][lr] = v0.x; As[lk + 1][lr] = v0.y; As[lk + 2][lr] = v0.z; As[lk + 3][lr] = v0.w;
        As[lk + 4][lr] = v1.x; As[lk + 5][lr] = v1.y; As[lk + 6][lr] = v1.z; As[lk + 7][lr] = v1.w;

        float4 w0 = *(const float4*)(W2 + (size_t)(kc + wk) * OC + col0 + wj);
        *(float4*)&Bs[wk][wj] = w0;
        __syncthreads();

        #pragma unroll
        for (int kk = 0; kk < 16; kk++) {
            float a[8], b[4];
            *(float4*)&a[0] = *(const float4*)&As[kk][ty * 8];
            *(float4*)&a[4] = *(const float4*)&As[kk][ty * 8 + 4];
            *(float4*)&b[0] = *(const float4*)&Bs[kk][tx * 4];
            #pragma unroll
            for (int i = 0; i < 8; i++)
                #pragma unroll
                for (int j = 0; j < 4; j++) acc[i][j] += a[i] * b[j];
        }
        __syncthreads();
    }

    #pragma unroll
    for (int i = 0; i < 8; i++) {
        int row = row0 + ty * 8 + i;
        if (row < n) {
            float* po = h2 + (size_t)row * OC + col0 + tx * 4;
            *(float4*)(po) = make_float4(acc[i][0], acc[i][1], acc[i][2], acc[i][3]);
        }
    }
}

// ---------------- attention scores: a_s4 [N,4] (padded), a_d [N,3] ----------------
__global__ __launch_bounds__(256) void k_att(const float* __restrict__ h2, const float* __restrict__ att_s,
                                             const float* __restrict__ att_d, float* __restrict__ a_s4,
                                             float* __restrict__ a_d, int n) {
    int w = (blockIdx.x * 256 + threadIdx.x) >> 6;
    int lane = threadIdx.x & 63;
    if (w >= n) return;
    #pragma unroll
    for (int hd = 0; hd < HEADS; hd++) {
        float hv = h2[(size_t)w * OC + hd * HC + lane];
        float vs = hv * att_s[hd * HC + lane];
        float vd = hv * att_d[hd * HC + lane];
        #pragma unroll
        for (int o = 32; o > 0; o >>= 1) {
            vs += __shfl_xor(vs, o, 64);
            vd += __shfl_xor(vd, o, 64);
        }
        if (lane == 0) {
            a_s4[w * 4 + hd] = vs;
            a_d[w * HEADS + hd] = vd;
        }
    }
    if (lane == 0) a_s4[w * 4 + 3] = 0.f;  // pad (never used in math)
}

__device__ __forceinline__ float lrelu(float v) { return v > 0.f ? v : NEG_SLOPE * v; }

// ---------------- GAT aggregate: single-pass online softmax (defer-max THR=8), unroll-4 ----------------
#define GAT_UPD(aa, hv0, hv1, hv2) do { \
    float ee0 = lrelu((aa).x + ad0); \
    float ee1 = lrelu((aa).y + ad1); \
    float ee2 = lrelu((aa).z + ad2); \
    if (ee0 > m0 + 8.0f) { float sc = __expf(m0 - ee0); s0 *= sc; acc0 *= sc; m0 = ee0; } \
    if (ee1 > m1 + 8.0f) { float sc = __expf(m1 - ee1); s1 *= sc; acc1 *= sc; m1 = ee1; } \
    if (ee2 > m2 + 8.0f) { float sc = __expf(m2 - ee2); s2 *= sc; acc2 *= sc; m2 = ee2; } \
    float w0 = __expf(ee0 - m0); \
    float w1 = __expf(ee1 - m1); \
    float w2 = __expf(ee2 - m2); \
    s0 += w0; s1 += w1; s2 += w2; \
    acc0 = fmaf(w0, (hv0), acc0); \
    acc1 = fmaf(w1, (hv1), acc1); \
    acc2 = fmaf(w2, (hv2), acc2); \
} while (0)

__global__ __launch_bounds__(256) void k_gat(const float* __restrict__ h2, const int* __restrict__ csr,
                                             const int* __restrict__ off, const float* __restrict__ a_s4,
                                             const float* __restrict__ a_d, const float* __restrict__ b2,
                                             float* __restrict__ out, int n) {
    int w = (blockIdx.x * 256 + threadIdx.x) >> 6;
    int lane = threadIdx.x & 63;
    if (w >= n) return;

    float ad0 = a_d[w * HEADS + 0];
    float ad1 = a_d[w * HEADS + 1];
    float ad2 = a_d[w * HEADS + 2];
    float4 asw = *(const float4*)(a_s4 + (size_t)w * 4);
    // self-loop score; init online-softmax state with self term (weight exp(0)=1)
    float m0 = lrelu(asw.x + ad0);
    float m1 = lrelu(asw.y + ad1);
    float m2 = lrelu(asw.z + ad2);
    float s0 = 1.f, s1 = 1.f, s2 = 1.f;
    const float* pself = h2 + (size_t)w * OC;
    float acc0 = pself[lane];
    float acc1 = pself[HC + lane];
    float acc2 = pself[2 * HC + lane];

    int beg = off[w], end = off[w + 1];
    int i = beg;
    for (; i + 4 <= end; i += 4) {
        int sA = csr[i], sB = csr[i + 1], sC = csr[i + 2], sD = csr[i + 3];
        float4 aA = *(const float4*)(a_s4 + (size_t)sA * 4);
        float4 aB = *(const float4*)(a_s4 + (size_t)sB * 4);
        float4 aC = *(const float4*)(a_s4 + (size_t)sC * 4);
        float4 aD = *(const float4*)(a_s4 + (size_t)sD * 4);
        const float* pA = h2 + (size_t)sA * OC;
        const float* pB = h2 + (size_t)sB * OC;
        const float* pC = h2 + (size_t)sC * OC;
        const float* pD = h2 + (size_t)sD * OC;
        float hA0 = pA[lane], hA1 = pA[HC + lane], hA2 = pA[2 * HC + lane];
        float hB0 = pB[lane], hB1 = pB[HC + lane], hB2 = pB[2 * HC + lane];
        float hC0 = pC[lane], hC1 = pC[HC + lane], hC2 = pC[2 * HC + lane];
        float hD0 = pD[lane], hD1 = pD[HC + lane], hD2 = pD[2 * HC + lane];
        GAT_UPD(aA, hA0, hA1, hA2);
        GAT_UPD(aB, hB0, hB1, hB2);
        GAT_UPD(aC, hC0, hC1, hC2);
        GAT_UPD(aD, hD0, hD1, hD2);
    }
    for (; i < end; i++) {
        int s = csr[i];
        float4 aa = *(const float4*)(a_s4 + (size_t)s * 4);
        const float* p = h2 + (size_t)s * OC;
        float h0 = p[lane], h1 = p[HC + lane], h2v = p[2 * HC + lane];
        GAT_UPD(aa, h0, h1, h2v);
    }

    float o0 = acc0 / s0 + b2[lane];
    float o1 = acc1 / s1 + b2[HC + lane];
    float o2 = acc2 / s2 + b2[2 * HC + lane];
    out[(size_t)w * OC + lane]          = fmaxf(o0, 0.f);
    out[(size_t)w * OC + HC + lane]     = fmaxf(o1, 0.f);
    out[(size_t)w * OC + 2 * HC + lane] = fmaxf(o2, 0.f);
}

// ---------------- launcher ----------------
extern "C" void kernel_launch(void* const* d_in, const int* in_sizes, int n_in,
                              void* d_out, int out_size, void* d_ws, size_t ws_size,
                              hipStream_t stream) {
    const float* x        = (const float*)d_in[0];
    const int*   ei       = (const int*)d_in[1];
    const float* W1       = (const float*)d_in[2];
    const float* b1       = (const float*)d_in[3];
    const float* W2       = (const float*)d_in[4];
    const float* att_src  = (const float*)d_in[5];
    const float* att_dst  = (const float*)d_in[6];
    const float* b2       = (const float*)d_in[7];
    float* out = (float*)d_out;

    const int n = in_sizes[0] / IN_CH;     // 50000
    const int E = in_sizes[1] / 2;         // 800000
    const int* src = ei;
    const int* dst = ei + E;

    // workspace layout (bytes), all offsets 256-aligned
    char* ws = (char*)d_ws;
    int*   cnt  = (int*)(ws + 0);                   // 50000 int
    int*   fill = (int*)(ws + 200192);              // 50000 int
    int*   off  = (int*)(ws + 400384);              // 50001 int
    float* dinv = (float*)(ws + 600576);            // 50000 f
    int*   csr  = (int*)(ws + 800768);              // 800000 int
    float* xw   = (float*)(ws + 4000768);           // 50000*128 f (pre-scaled by dinv)
    float* h    = (float*)(ws + 29600768);          // 50000*128 f
    float* h2   = (float*)(ws + 55200768);          // 50000*192 f
    float* a_s4 = (float*)(ws + 93600768);          // 50000*4 f (padded)
    float* a_d  = (float*)(ws + 94400768);          // 50000*3 f
    // total ~95.0 MB

    hipMemsetAsync(ws, 0, 400384, stream);          // cnt + fill

    int egrid = (E + 255) / 256;
    k_hist<<<egrid, 256, 0, stream>>>(dst, E, cnt);
    k_scan<<<1, 1024, 0, stream>>>(cnt, off, dinv, n);
    k_fill<<<egrid, 256, 0, stream>>>(src, dst, E, off, fill, csr);

    int g1 = (n + 127) / 128;
    k_gemm1<<<g1, 256, 0, stream>>>(x, W1, dinv, xw, n);

    int ngrid = (n + 3) / 4;   // 4 waves per block
    k_gcn<<<ngrid, 256, 0, stream>>>(xw, csr, off, dinv, b1, h, n);

    dim3 g2((n + 127) / 128, 3);
    k_gemm2<<<g2, 256, 0, stream>>>(h, W2, h2, n);

    k_att<<<ngrid, 256, 0, stream>>>(h2, att_src, att_dst, a_s4, a_d, n);
    k_gat<<<ngrid, 256, 0, stream>>>(h2, csr, off, a_s4, a_d, b2, out, n);
}

// Round 3
// 389.132 us; speedup vs baseline: 1.3672x; 1.0510x over previous
//
#include <hip/hip_runtime.h>
#include <math.h>

// Problem constants (verified against reference setup_inputs)
#define NODES    50000
#define IN_CH    256
#define HID      128
#define HEADS    3
#define HC       64
#define OC       (HEADS*HC)   // 192
#define NEG_SLOPE 0.2f

__device__ __forceinline__ float lrelu(float v) { return v > 0.f ? v : NEG_SLOPE * v; }

// ---------------- CSR build ----------------

__global__ __launch_bounds__(256) void k_hist(const int* __restrict__ dst, int E, int* __restrict__ cnt) {
    int e = blockIdx.x * 256 + threadIdx.x;
    if (e < E) atomicAdd(&cnt[dst[e]], 1);
}

// Per-block scan (1024 elems/block): off[i] = local exclusive, bsum[b] = block total, dinv.
__global__ __launch_bounds__(1024) void k_scanA(const int* __restrict__ cnt, int* __restrict__ off,
                                                float* __restrict__ dinv, int* __restrict__ bsum, int n) {
    __shared__ int wsums[16];
    int tid = threadIdx.x, lane = tid & 63, wid = tid >> 6;
    int i = blockIdx.x * 1024 + tid;
    int v = (i < n) ? cnt[i] : 0;
    int incl = v;
    #pragma unroll
    for (int d = 1; d < 64; d <<= 1) {
        int t = __shfl_up(incl, d, 64);
        if (lane >= d) incl += t;
    }
    if (lane == 63) wsums[wid] = incl;
    __syncthreads();
    if (tid == 0) {
        int run = 0;
        #pragma unroll
        for (int j = 0; j < 16; j++) { int t = wsums[j]; wsums[j] = run; run += t; }
        bsum[blockIdx.x] = run;
    }
    __syncthreads();
    if (i < n) {
        off[i] = wsums[wid] + incl - v;
        dinv[i] = rsqrtf((float)(v + 1));   // +1 for self loop
    }
}

// Single-wave scan of block sums (nb <= 64).
__global__ __launch_bounds__(64) void k_scanB(const int* __restrict__ bsum, int* __restrict__ bbase,
                                              int* __restrict__ off, int nb, int n) {
    int tid = threadIdx.x;
    int v = (tid < nb) ? bsum[tid] : 0;
    int incl = v;
    #pragma unroll
    for (int d = 1; d < 64; d <<= 1) {
        int t = __shfl_up(incl, d, 64);
        if (tid >= d) incl += t;
    }
    bbase[tid] = incl - v;
    if (tid == 63) off[n] = incl;   // grand total = E
}

__global__ __launch_bounds__(256) void k_scanC(int* __restrict__ off, const int* __restrict__ bbase, int n) {
    int i = blockIdx.x * 256 + threadIdx.x;
    if (i < n) off[i] += bbase[i >> 10];
}

__global__ __launch_bounds__(256) void k_fill(const int* __restrict__ src, const int* __restrict__ dst, int E,
                                              const int* __restrict__ off, int* __restrict__ fill,
                                              int* __restrict__ csr, int* __restrict__ dstv) {
    int e = blockIdx.x * 256 + threadIdx.x;
    if (e < E) {
        int d = dst[e];
        int p = off[d] + atomicAdd(&fill[d], 1);
        csr[p] = src[e];
        dstv[p] = d;
    }
}

// ---------------- GEMM1: xw = dinv[row] * (x @ W1)   [N,256]x[256,128] ----------------
__global__ __launch_bounds__(256) void k_gemm1(const float* __restrict__ x, const float* __restrict__ W1,
                                               const float* __restrict__ dinv,
                                               float* __restrict__ xw, int n) {
    __shared__ float As[16][128];  // [kk][row]
    __shared__ float Bs[16][128];  // [kk][col]
    int tid = threadIdx.x;
    int tx = tid & 15, ty = tid >> 4;
    int row0 = blockIdx.x * 128;

    float acc[8][8];
    #pragma unroll
    for (int i = 0; i < 8; i++)
        #pragma unroll
        for (int j = 0; j < 8; j++) acc[i][j] = 0.f;

    int lr = tid >> 1;              // row for x load
    int lk = (tid & 1) * 8;         // k offset for x load
    int wk = tid >> 4;              // k row for W load
    int wj = (tid & 15) * 8;        // col for W load

    for (int kc = 0; kc < IN_CH; kc += 16) {
        int grow = row0 + lr;
        float4 v0, v1;
        if (grow < n) {
            const float* p = x + (size_t)grow * IN_CH + kc + lk;
            v0 = *(const float4*)(p);
            v1 = *(const float4*)(p + 4);
        } else {
            v0 = make_float4(0.f, 0.f, 0.f, 0.f);
            v1 = v0;
        }
        As[lk + 0][lr] = v0.x; As[lk + 1][lr] = v0.y; As[lk + 2][lr] = v0.z; As[lk + 3][lr] = v0.w;
        As[lk + 4][lr] = v1.x; As[lk + 5][lr] = v1.y; As[lk + 6][lr] = v1.z; As[lk + 7][lr] = v1.w;

        const float* wp = W1 + (size_t)(kc + wk) * HID + wj;
        float4 w0 = *(const float4*)(wp);
        float4 w1 = *(const float4*)(wp + 4);
        *(float4*)&Bs[wk][wj] = w0;
        *(float4*)&Bs[wk][wj + 4] = w1;
        __syncthreads();

        #pragma unroll
        for (int kk = 0; kk < 16; kk++) {
            float a[8], b[8];
            *(float4*)&a[0] = *(const float4*)&As[kk][ty * 8];
            *(float4*)&a[4] = *(const float4*)&As[kk][ty * 8 + 4];
            *(float4*)&b[0] = *(const float4*)&Bs[kk][tx * 8];
            *(float4*)&b[4] = *(const float4*)&Bs[kk][tx * 8 + 4];
            #pragma unroll
            for (int i = 0; i < 8; i++)
                #pragma unroll
                for (int j = 0; j < 8; j++) acc[i][j] += a[i] * b[j];
        }
        __syncthreads();
    }

    #pragma unroll
    for (int i = 0; i < 8; i++) {
        int row = row0 + ty * 8 + i;
        if (row < n) {
            float sc = dinv[row];
            float* po = xw + (size_t)row * HID + tx * 8;
            *(float4*)(po)     = make_float4(sc*acc[i][0], sc*acc[i][1], sc*acc[i][2], sc*acc[i][3]);
            *(float4*)(po + 4) = make_float4(sc*acc[i][4], sc*acc[i][5], sc*acc[i][6], sc*acc[i][7]);
        }
    }
}

// ---------------- GCN aggregate: wave/node, pair-edge float4 lanes ----------------
// lanes 0-31 handle edge i (float4 over 128 cols), lanes 32-63 edge i+1; shfl-combine at end.
__global__ __launch_bounds__(256) void k_gcn(const float* __restrict__ xw, const int* __restrict__ csr,
                                             const int* __restrict__ off, const float* __restrict__ dinv,
                                             const float* __restrict__ b1, float* __restrict__ h, int n) {
    int w = (blockIdx.x * 256 + threadIdx.x) >> 6;
    int lane = threadIdx.x & 63;
    if (w >= n) return;
    int half = lane >> 5;
    int c4 = (lane & 31) * 4;
    float di = dinv[w];
    float a0 = 0.f, a1 = 0.f, a2 = 0.f, a3 = 0.f;
    int beg = off[w], end = off[w + 1];
    int i = beg;
    for (; i + 8 <= end; i += 8) {
        int s0 = csr[i + half];
        int s1 = csr[i + 2 + half];
        int s2 = csr[i + 4 + half];
        int s3 = csr[i + 6 + half];
        float4 v0 = *(const float4*)(xw + (size_t)s0 * HID + c4);
        float4 v1 = *(const float4*)(xw + (size_t)s1 * HID + c4);
        float4 v2 = *(const float4*)(xw + (size_t)s2 * HID + c4);
        float4 v3 = *(const float4*)(xw + (size_t)s3 * HID + c4);
        a0 += v0.x + v1.x + v2.x + v3.x;
        a1 += v0.y + v1.y + v2.y + v3.y;
        a2 += v0.z + v1.z + v2.z + v3.z;
        a3 += v0.w + v1.w + v2.w + v3.w;
    }
    for (; i + 2 <= end; i += 2) {
        int s = csr[i + half];
        float4 v = *(const float4*)(xw + (size_t)s * HID + c4);
        a0 += v.x; a1 += v.y; a2 += v.z; a3 += v.w;
    }
    if (i < end && half == 0) {
        int s = csr[i];
        float4 v = *(const float4*)(xw + (size_t)s * HID + c4);
        a0 += v.x; a1 += v.y; a2 += v.z; a3 += v.w;
    }
    a0 += __shfl_xor(a0, 32, 64);
    a1 += __shfl_xor(a1, 32, 64);
    a2 += __shfl_xor(a2, 32, 64);
    a3 += __shfl_xor(a3, 32, 64);
    if (half == 0) {
        float4 vs = *(const float4*)(xw + (size_t)w * HID + c4);   // self (pre-scaled)
        float4 bb = *(const float4*)(b1 + c4);
        float4 o;
        o.x = fmaxf(fmaf(di, a0 + vs.x, bb.x), 0.f);
        o.y = fmaxf(fmaf(di, a1 + vs.y, bb.y), 0.f);
        o.z = fmaxf(fmaf(di, a2 + vs.z, bb.z), 0.f);
        o.w = fmaxf(fmaf(di, a3 + vs.w, bb.w), 0.f);
        *(float4*)(h + (size_t)w * HID + c4) = o;
    }
}

// ---------------- GEMM2: h2 = h @ W2   [N,128]x[128,192] ----------------
__global__ __launch_bounds__(256) void k_gemm2(const float* __restrict__ h, const float* __restrict__ W2,
                                               float* __restrict__ h2, int n) {
    __shared__ float As[16][128];
    __shared__ float Bs[16][64];
    int tid = threadIdx.x;
    int tx = tid & 15, ty = tid >> 4;
    int row0 = blockIdx.x * 128;
    int col0 = blockIdx.y * 64;

    float acc[8][4];
    #pragma unroll
    for (int i = 0; i < 8; i++)
        #pragma unroll
        for (int j = 0; j < 4; j++) acc[i][j] = 0.f;

    int lr = tid >> 1;
    int lk = (tid & 1) * 8;
    int wk = tid >> 4;
    int wj = (tid & 15) * 4;

    for (int kc = 0; kc < HID; kc += 16) {
        int grow = row0 + lr;
        float4 v0, v1;
        if (grow < n) {
            const float* p = h + (size_t)grow * HID + kc + lk;
            v0 = *(const float4*)(p);
            v1 = *(const float4*)(p + 4);
        } else {
            v0 = make_float4(0.f, 0.f, 0.f, 0.f);
            v1 = v0;
        }
        As[lk + 0][lr] = v0.x; As[lk + 1][lr] = v0.y; As[lk + 2][lr] = v0.z; As[lk + 3][lr] = v0.w;
        As[lk + 4][lr] = v1.x; As[lk + 5][lr] = v1.y; As[lk + 6][lr] = v1.z; As[lk + 7][lr] = v1.w;

        float4 w0 = *(const float4*)(W2 + (size_t)(kc + wk) * OC + col0 + wj);
        *(float4*)&Bs[wk][wj] = w0;
        __syncthreads();

        #pragma unroll
        for (int kk = 0; kk < 16; kk++) {
            float a[8], b[4];
            *(float4*)&a[0] = *(const float4*)&As[kk][ty * 8];
            *(float4*)&a[4] = *(const float4*)&As[kk][ty * 8 + 4];
            *(float4*)&b[0] = *(const float4*)&Bs[kk][tx * 4];
            #pragma unroll
            for (int i = 0; i < 8; i++)
                #pragma unroll
                for (int j = 0; j < 4; j++) acc[i][j] += a[i] * b[j];
        }
        __syncthreads();
    }

    #pragma unroll
    for (int i = 0; i < 8; i++) {
        int row = row0 + ty * 8 + i;
        if (row < n) {
            float* po = h2 + (size_t)row * OC + col0 + tx * 4;
            *(float4*)(po) = make_float4(acc[i][0], acc[i][1], acc[i][2], acc[i][3]);
        }
    }
}

// ---------------- attention scores: a_s4 [N,4], a_d4 [N,4] (padded) ----------------
__global__ __launch_bounds__(256) void k_att(const float* __restrict__ h2, const float* __restrict__ att_s,
                                             const float* __restrict__ att_d, float* __restrict__ a_s4,
                                             float* __restrict__ a_d4, int n) {
    int w = (blockIdx.x * 256 + threadIdx.x) >> 6;
    int lane = threadIdx.x & 63;
    if (w >= n) return;
    #pragma unroll
    for (int hd = 0; hd < HEADS; hd++) {
        float hv = h2[(size_t)w * OC + hd * HC + lane];
        float vs = hv * att_s[hd * HC + lane];
        float vd = hv * att_d[hd * HC + lane];
        #pragma unroll
        for (int o = 32; o > 0; o >>= 1) {
            vs += __shfl_xor(vs, o, 64);
            vd += __shfl_xor(vd, o, 64);
        }
        if (lane == 0) {
            a_s4[w * 4 + hd] = vs;
            a_d4[w * 4 + hd] = vd;
        }
    }
    if (lane == 0) { a_s4[w * 4 + 3] = 0.f; a_d4[w * 4 + 3] = 0.f; }
}

// ---------------- global per-head max of a_s (single block) ----------------
__global__ __launch_bounds__(1024) void k_asmax(const float* __restrict__ a_s4, int n, float* __restrict__ asmax) {
    float m0 = -1e30f, m1 = -1e30f, m2 = -1e30f;
    for (int i = threadIdx.x; i < n; i += 1024) {
        float4 v = *(const float4*)(a_s4 + (size_t)i * 4);
        m0 = fmaxf(m0, v.x); m1 = fmaxf(m1, v.y); m2 = fmaxf(m2, v.z);
    }
    #pragma unroll
    for (int o = 32; o > 0; o >>= 1) {
        m0 = fmaxf(m0, __shfl_xor(m0, o, 64));
        m1 = fmaxf(m1, __shfl_xor(m1, o, 64));
        m2 = fmaxf(m2, __shfl_xor(m2, o, 64));
    }
    __shared__ float sm[16][3];
    int lane = threadIdx.x & 63, wid = threadIdx.x >> 6;
    if (lane == 0) { sm[wid][0] = m0; sm[wid][1] = m1; sm[wid][2] = m2; }
    __syncthreads();
    if (threadIdx.x == 0) {
        for (int j = 1; j < 16; j++) {
            m0 = fmaxf(m0, sm[j][0]); m1 = fmaxf(m1, sm[j][1]); m2 = fmaxf(m2, sm[j][2]);
        }
        asmax[0] = m0; asmax[1] = m1; asmax[2] = m2;
    }
}

// ---------------- edge-parallel softmax weights ----------------
// w_h = exp(lrelu(a_s[s]+a_d[d]) - C_d,h), C_d,h = lrelu(asmax_h + a_d[d]) >= any score at d
// (per-dst constant shift -> cancels in softmax; all weights <= 1)
__global__ __launch_bounds__(256) void k_edgew(const int* __restrict__ csr, const int* __restrict__ dstv,
                                               const float* __restrict__ a_s4, const float* __restrict__ a_d4,
                                               const float* __restrict__ asmax, int E, float* __restrict__ w4) {
    int p = blockIdx.x * 256 + threadIdx.x;
    if (p >= E) return;
    int s = csr[p], d = dstv[p];
    float4 as = *(const float4*)(a_s4 + (size_t)s * 4);
    float4 ad = *(const float4*)(a_d4 + (size_t)d * 4);
    float m0 = asmax[0], m1 = asmax[1], m2 = asmax[2];
    float4 wv;
    wv.x = __expf(lrelu(as.x + ad.x) - lrelu(m0 + ad.x));
    wv.y = __expf(lrelu(as.y + ad.y) - lrelu(m1 + ad.y));
    wv.z = __expf(lrelu(as.z + ad.z) - lrelu(m2 + ad.z));
    wv.w = 0.f;
    *(float4*)(w4 + (size_t)p * 4) = wv;
}

// ---------------- GAT aggregate: wave/node, precomputed weights, float4 lanes ----------------
// lane l<48 covers cols 4l..4l+3 (head = l/16); lanes 48-63 mirror head0 (stores masked).
__global__ __launch_bounds__(256) void k_gat(const float* __restrict__ h2, const int* __restrict__ csr,
                                             const int* __restrict__ off, const float* __restrict__ w4,
                                             const float* __restrict__ a_s4, const float* __restrict__ a_d4,
                                             const float* __restrict__ asmax, const float* __restrict__ b2,
                                             float* __restrict__ out, int n) {
    int w = (blockIdx.x * 256 + threadIdx.x) >> 6;
    int lane = threadIdx.x & 63;
    if (w >= n) return;
    bool g1 = lane >= 16, g2 = lane >= 32;
    bool act = lane < 48;
    int ll = act ? lane : (lane - 48);
    int c4 = ll * 4;

    // self-loop weight
    float4 asw = *(const float4*)(a_s4 + (size_t)w * 4);
    float4 adw = *(const float4*)(a_d4 + (size_t)w * 4);
    float ws0 = __expf(lrelu(asw.x + adw.x) - lrelu(asmax[0] + adw.x));
    float ws1 = __expf(lrelu(asw.y + adw.y) - lrelu(asmax[1] + adw.y));
    float ws2 = __expf(lrelu(asw.z + adw.z) - lrelu(asmax[2] + adw.z));
    float wsl = g2 ? ws2 : (g1 ? ws1 : ws0);
    float ssum = wsl;
    float4 hv = *(const float4*)(h2 + (size_t)w * OC + c4);
    float a0 = wsl * hv.x, a1 = wsl * hv.y, a2 = wsl * hv.z, a3 = wsl * hv.w;

    int beg = off[w], end = off[w + 1];
    int i = beg;
    for (; i + 4 <= end; i += 4) {
        int sA = csr[i], sB = csr[i + 1], sC = csr[i + 2], sD = csr[i + 3];
        float4 wA = *(const float4*)(w4 + (size_t)(i + 0) * 4);
        float4 wB = *(const float4*)(w4 + (size_t)(i + 1) * 4);
        float4 wC = *(const float4*)(w4 + (size_t)(i + 2) * 4);
        float4 wD = *(const float4*)(w4 + (size_t)(i + 3) * 4);
        float4 hA = *(const float4*)(h2 + (size_t)sA * OC + c4);
        float4 hB = *(const float4*)(h2 + (size_t)sB * OC + c4);
        float4 hC = *(const float4*)(h2 + (size_t)sC * OC + c4);
        float4 hD = *(const float4*)(h2 + (size_t)sD * OC + c4);
        float wlA = g2 ? wA.z : (g1 ? wA.y : wA.x);
        float wlB = g2 ? wB.z : (g1 ? wB.y : wB.x);
        float wlC = g2 ? wC.z : (g1 ? wC.y : wC.x);
        float wlD = g2 ? wD.z : (g1 ? wD.y : wD.x);
        ssum += wlA + wlB + wlC + wlD;
        a0 = fmaf(wlA, hA.x, a0); a1 = fmaf(wlA, hA.y, a1); a2 = fmaf(wlA, hA.z, a2); a3 = fmaf(wlA, hA.w, a3);
        a0 = fmaf(wlB, hB.x, a0); a1 = fmaf(wlB, hB.y, a1); a2 = fmaf(wlB, hB.z, a2); a3 = fmaf(wlB, hB.w, a3);
        a0 = fmaf(wlC, hC.x, a0); a1 = fmaf(wlC, hC.y, a1); a2 = fmaf(wlC, hC.z, a2); a3 = fmaf(wlC, hC.w, a3);
        a0 = fmaf(wlD, hD.x, a0); a1 = fmaf(wlD, hD.y, a1); a2 = fmaf(wlD, hD.z, a2); a3 = fmaf(wlD, hD.w, a3);
    }
    for (; i < end; i++) {
        int s = csr[i];
        float4 wv = *(const float4*)(w4 + (size_t)i * 4);
        float4 hv2 = *(const float4*)(h2 + (size_t)s * OC + c4);
        float wl = g2 ? wv.z : (g1 ? wv.y : wv.x);
        ssum += wl;
        a0 = fmaf(wl, hv2.x, a0); a1 = fmaf(wl, hv2.y, a1); a2 = fmaf(wl, hv2.z, a2); a3 = fmaf(wl, hv2.w, a3);
    }

    if (act) {
        float inv = 1.f / ssum;
        float4 bb = *(const float4*)(b2 + c4);
        float4 o;
        o.x = fmaxf(fmaf(a0, inv, bb.x), 0.f);
        o.y = fmaxf(fmaf(a1, inv, bb.y), 0.f);
        o.z = fmaxf(fmaf(a2, inv, bb.z), 0.f);
        o.w = fmaxf(fmaf(a3, inv, bb.w), 0.f);
        *(float4*)(out + (size_t)w * OC + c4) = o;
    }
}

// ---------------- launcher ----------------
extern "C" void kernel_launch(void* const* d_in, const int* in_sizes, int n_in,
                              void* d_out, int out_size, void* d_ws, size_t ws_size,
                              hipStream_t stream) {
    const float* x        = (const float*)d_in[0];
    const int*   ei       = (const int*)d_in[1];
    const float* W1       = (const float*)d_in[2];
    const float* b1       = (const float*)d_in[3];
    const float* W2       = (const float*)d_in[4];
    const float* att_src  = (const float*)d_in[5];
    const float* att_dst  = (const float*)d_in[6];
    const float* b2       = (const float*)d_in[7];
    float* out = (float*)d_out;

    const int n = in_sizes[0] / IN_CH;     // 50000
    const int E = in_sizes[1] / 2;         // 800000
    const int* src = ei;
    const int* dst = ei + E;

    // workspace layout (bytes), 256-aligned
    char* ws = (char*)d_ws;
    int*   cnt   = (int*)(ws + 0);               // 50000 i
    int*   fill  = (int*)(ws + 200192);          // 50000 i
    int*   off   = (int*)(ws + 400384);          // 50001 i
    float* dinv  = (float*)(ws + 600832);        // 50000 f
    int*   bsum  = (int*)(ws + 801024);          // 49 i
    int*   bbase = (int*)(ws + 801280);          // 64 i
    float* asmax = (float*)(ws + 801536);        // 3 f
    int*   csr   = (int*)(ws + 801792);          // 800000 i
    int*   dstv  = (int*)(ws + 4001792);         // 800000 i
    float* a_s4  = (float*)(ws + 7201792);       // 50000*4 f
    float* a_d4  = (float*)(ws + 8001792);       // 50000*4 f
    float* xw    = (float*)(ws + 8801792);       // 50000*128 f (pre-scaled by dinv)
    float* w4    = (float*)(ws + 8801792);       // 800000*4 f -- ALIASES xw (xw dead after k_gcn)
    float* h     = (float*)(ws + 34401792);      // 50000*128 f
    float* h2    = (float*)(ws + 60001792);      // 50000*192 f
    // total ~98.4 MB

    hipMemsetAsync(ws, 0, 400384, stream);       // cnt + fill

    int egrid = (E + 255) / 256;
    int nb = (n + 1023) / 1024;                  // 49
    k_hist<<<egrid, 256, 0, stream>>>(dst, E, cnt);
    k_scanA<<<nb, 1024, 0, stream>>>(cnt, off, dinv, bsum, n);
    k_scanB<<<1, 64, 0, stream>>>(bsum, bbase, off, nb, n);
    k_scanC<<<(n + 255) / 256, 256, 0, stream>>>(off, bbase, n);
    k_fill<<<egrid, 256, 0, stream>>>(src, dst, E, off, fill, csr, dstv);

    int g1 = (n + 127) / 128;
    k_gemm1<<<g1, 256, 0, stream>>>(x, W1, dinv, xw, n);

    int ngrid = (n + 3) / 4;   // 4 waves per block
    k_gcn<<<ngrid, 256, 0, stream>>>(xw, csr, off, dinv, b1, h, n);

    dim3 g2((n + 127) / 128, 3);
    k_gemm2<<<g2, 256, 0, stream>>>(h, W2, h2, n);

    k_att<<<ngrid, 256, 0, stream>>>(h2, att_src, att_dst, a_s4, a_d4, n);
    k_asmax<<<1, 1024, 0, stream>>>(a_s4, n, asmax);
    k_edgew<<<egrid, 256, 0, stream>>>(csr, dstv, a_s4, a_d4, asmax, E, w4);
    k_gat<<<ngrid, 256, 0, stream>>>(h2, csr, off, w4, a_s4, a_d4, asmax, b2, out, n);
}

// Round 4
// 343.324 us; speedup vs baseline: 1.5497x; 1.1334x over previous
//
#include <hip/hip_runtime.h>
#include <hip/hip_fp16.h>
#include <math.h>

// Problem constants (verified against reference setup_inputs)
#define NODES    50000
#define IN_CH    256
#define HID      128
#define HEADS    3
#define HC       64
#define OC       (HEADS*HC)   // 192
#define NEG_SLOPE 0.2f

__device__ __forceinline__ float lrelu(float v) { return v > 0.f ? v : NEG_SLOPE * v; }

// ---- fp16 pack helpers ----
__device__ __forceinline__ float4 ld_half4(const __half* p) {
    float2 raw = *(const float2*)p;                       // one 8B load
    const __half2* h = reinterpret_cast<const __half2*>(&raw);
    float2 a = __half22float2(h[0]);
    float2 b = __half22float2(h[1]);
    return make_float4(a.x, a.y, b.x, b.y);
}
__device__ __forceinline__ void st_half4(__half* p, float x, float y, float z, float w) {
    __half2 h0 = __floats2half2_rn(x, y);
    __half2 h1 = __floats2half2_rn(z, w);
    float2 raw;
    raw.x = *reinterpret_cast<float*>(&h0);
    raw.y = *reinterpret_cast<float*>(&h1);
    *(float2*)p = raw;                                    // one 8B store
}

// ---------------- CSR build ----------------

__global__ __launch_bounds__(256) void k_hist(const int* __restrict__ dst, int E, int* __restrict__ cnt) {
    int e = blockIdx.x * 256 + threadIdx.x;
    if (e < E) atomicAdd(&cnt[dst[e]], 1);
}

// Per-block scan (1024 elems/block): off[i] = local exclusive, bsum[b] = block total, dinv.
__global__ __launch_bounds__(1024) void k_scanA(const int* __restrict__ cnt, int* __restrict__ off,
                                                float* __restrict__ dinv, int* __restrict__ bsum, int n) {
    __shared__ int wsums[16];
    int tid = threadIdx.x, lane = tid & 63, wid = tid >> 6;
    int i = blockIdx.x * 1024 + tid;
    int v = (i < n) ? cnt[i] : 0;
    int incl = v;
    #pragma unroll
    for (int d = 1; d < 64; d <<= 1) {
        int t = __shfl_up(incl, d, 64);
        if (lane >= d) incl += t;
    }
    if (lane == 63) wsums[wid] = incl;
    __syncthreads();
    if (tid == 0) {
        int run = 0;
        #pragma unroll
        for (int j = 0; j < 16; j++) { int t = wsums[j]; wsums[j] = run; run += t; }
        bsum[blockIdx.x] = run;
    }
    __syncthreads();
    if (i < n) {
        off[i] = wsums[wid] + incl - v;
        dinv[i] = rsqrtf((float)(v + 1));   // +1 for self loop
    }
}

// Single-wave scan of block sums (nb <= 64).
__global__ __launch_bounds__(64) void k_scanB(const int* __restrict__ bsum, int* __restrict__ bbase,
                                              int* __restrict__ off, int nb, int n) {
    int tid = threadIdx.x;
    int v = (tid < nb) ? bsum[tid] : 0;
    int incl = v;
    #pragma unroll
    for (int d = 1; d < 64; d <<= 1) {
        int t = __shfl_up(incl, d, 64);
        if (tid >= d) incl += t;
    }
    bbase[tid] = incl - v;
    if (tid == 63) off[n] = incl;   // grand total = E
}

__global__ __launch_bounds__(256) void k_scanC(int* __restrict__ off, const int* __restrict__ bbase, int n) {
    int i = blockIdx.x * 256 + threadIdx.x;
    if (i < n) off[i] += bbase[i >> 10];
}

__global__ __launch_bounds__(256) void k_fill(const int* __restrict__ src, const int* __restrict__ dst, int E,
                                              const int* __restrict__ off, int* __restrict__ fill,
                                              int* __restrict__ csr, int* __restrict__ dstv) {
    int e = blockIdx.x * 256 + threadIdx.x;
    if (e < E) {
        int d = dst[e];
        int p = off[d] + atomicAdd(&fill[d], 1);
        csr[p] = src[e];
        dstv[p] = d;
    }
}

// ---------------- GEMM1: xwh = fp16( dinv[row] * (x @ W1) )   [N,256]x[256,128] ----------------
__global__ __launch_bounds__(256) void k_gemm1(const float* __restrict__ x, const float* __restrict__ W1,
                                               const float* __restrict__ dinv,
                                               __half* __restrict__ xwh, int n) {
    __shared__ float As[16][128];  // [kk][row]
    __shared__ float Bs[16][128];  // [kk][col]
    int tid = threadIdx.x;
    int tx = tid & 15, ty = tid >> 4;
    int row0 = blockIdx.x * 128;

    float acc[8][8];
    #pragma unroll
    for (int i = 0; i < 8; i++)
        #pragma unroll
        for (int j = 0; j < 8; j++) acc[i][j] = 0.f;

    int lr = tid >> 1;              // row for x load
    int lk = (tid & 1) * 8;         // k offset for x load
    int wk = tid >> 4;              // k row for W load
    int wj = (tid & 15) * 8;        // col for W load

    for (int kc = 0; kc < IN_CH; kc += 16) {
        int grow = row0 + lr;
        float4 v0, v1;
        if (grow < n) {
            const float* p = x + (size_t)grow * IN_CH + kc + lk;
            v0 = *(const float4*)(p);
            v1 = *(const float4*)(p + 4);
        } else {
            v0 = make_float4(0.f, 0.f, 0.f, 0.f);
            v1 = v0;
        }
        As[lk + 0][lr] = v0.x; As[lk + 1][lr] = v0.y; As[lk + 2][lr] = v0.z; As[lk + 3][lr] = v0.w;
        As[lk + 4][lr] = v1.x; As[lk + 5][lr] = v1.y; As[lk + 6][lr] = v1.z; As[lk + 7][lr] = v1.w;

        const float* wp = W1 + (size_t)(kc + wk) * HID + wj;
        float4 w0 = *(const float4*)(wp);
        float4 w1 = *(const float4*)(wp + 4);
        *(float4*)&Bs[wk][wj] = w0;
        *(float4*)&Bs[wk][wj + 4] = w1;
        __syncthreads();

        #pragma unroll
        for (int kk = 0; kk < 16; kk++) {
            float a[8], b[8];
            *(float4*)&a[0] = *(const float4*)&As[kk][ty * 8];
            *(float4*)&a[4] = *(const float4*)&As[kk][ty * 8 + 4];
            *(float4*)&b[0] = *(const float4*)&Bs[kk][tx * 8];
            *(float4*)&b[4] = *(const float4*)&Bs[kk][tx * 8 + 4];
            #pragma unroll
            for (int i = 0; i < 8; i++)
                #pragma unroll
                for (int j = 0; j < 8; j++) acc[i][j] += a[i] * b[j];
        }
        __syncthreads();
    }

    #pragma unroll
    for (int i = 0; i < 8; i++) {
        int row = row0 + ty * 8 + i;
        if (row < n) {
            float sc = dinv[row];
            __half* po = xwh + (size_t)row * HID + tx * 8;
            st_half4(po,     sc*acc[i][0], sc*acc[i][1], sc*acc[i][2], sc*acc[i][3]);
            st_half4(po + 4, sc*acc[i][4], sc*acc[i][5], sc*acc[i][6], sc*acc[i][7]);
        }
    }
}

// ---------------- GCN aggregate: wave/node, pair-edge half4 lanes ----------------
// lanes 0-31 handle edge i (half4 over 128 cols), lanes 32-63 edge i+1; shfl-combine at end.
__global__ __launch_bounds__(256) void k_gcn(const __half* __restrict__ xwh, const int* __restrict__ csr,
                                             const int* __restrict__ off, const float* __restrict__ dinv,
                                             const float* __restrict__ b1, float* __restrict__ h, int n) {
    int w = (blockIdx.x * 256 + threadIdx.x) >> 6;
    int lane = threadIdx.x & 63;
    if (w >= n) return;
    int half = lane >> 5;
    int c4 = (lane & 31) * 4;
    float di = dinv[w];
    float a0 = 0.f, a1 = 0.f, a2 = 0.f, a3 = 0.f;
    int beg = off[w], end = off[w + 1];
    int i = beg;
    for (; i + 8 <= end; i += 8) {
        int s0 = csr[i + half];
        int s1 = csr[i + 2 + half];
        int s2 = csr[i + 4 + half];
        int s3 = csr[i + 6 + half];
        float4 v0 = ld_half4(xwh + (size_t)s0 * HID + c4);
        float4 v1 = ld_half4(xwh + (size_t)s1 * HID + c4);
        float4 v2 = ld_half4(xwh + (size_t)s2 * HID + c4);
        float4 v3 = ld_half4(xwh + (size_t)s3 * HID + c4);
        a0 += v0.x + v1.x + v2.x + v3.x;
        a1 += v0.y + v1.y + v2.y + v3.y;
        a2 += v0.z + v1.z + v2.z + v3.z;
        a3 += v0.w + v1.w + v2.w + v3.w;
    }
    for (; i + 2 <= end; i += 2) {
        int s = csr[i + half];
        float4 v = ld_half4(xwh + (size_t)s * HID + c4);
        a0 += v.x; a1 += v.y; a2 += v.z; a3 += v.w;
    }
    if (i < end && half == 0) {
        int s = csr[i];
        float4 v = ld_half4(xwh + (size_t)s * HID + c4);
        a0 += v.x; a1 += v.y; a2 += v.z; a3 += v.w;
    }
    a0 += __shfl_xor(a0, 32, 64);
    a1 += __shfl_xor(a1, 32, 64);
    a2 += __shfl_xor(a2, 32, 64);
    a3 += __shfl_xor(a3, 32, 64);
    if (half == 0) {
        float4 vs = ld_half4(xwh + (size_t)w * HID + c4);   // self (pre-scaled)
        float4 bb = *(const float4*)(b1 + c4);
        float4 o;
        o.x = fmaxf(fmaf(di, a0 + vs.x, bb.x), 0.f);
        o.y = fmaxf(fmaf(di, a1 + vs.y, bb.y), 0.f);
        o.z = fmaxf(fmaf(di, a2 + vs.z, bb.z), 0.f);
        o.w = fmaxf(fmaf(di, a3 + vs.w, bb.w), 0.f);
        *(float4*)(h + (size_t)w * HID + c4) = o;
    }
}

// ---------------- GEMM2: h2h = fp16( h @ W2 )   [N,128]x[128,192] ----------------
__global__ __launch_bounds__(256) void k_gemm2(const float* __restrict__ h, const float* __restrict__ W2,
                                               __half* __restrict__ h2h, int n) {
    __shared__ float As[16][128];
    __shared__ float Bs[16][64];
    int tid = threadIdx.x;
    int tx = tid & 15, ty = tid >> 4;
    int row0 = blockIdx.x * 128;
    int col0 = blockIdx.y * 64;

    float acc[8][4];
    #pragma unroll
    for (int i = 0; i < 8; i++)
        #pragma unroll
        for (int j = 0; j < 4; j++) acc[i][j] = 0.f;

    int lr = tid >> 1;
    int lk = (tid & 1) * 8;
    int wk = tid >> 4;
    int wj = (tid & 15) * 4;

    for (int kc = 0; kc < HID; kc += 16) {
        int grow = row0 + lr;
        float4 v0, v1;
        if (grow < n) {
            const float* p = h + (size_t)grow * HID + kc + lk;
            v0 = *(const float4*)(p);
            v1 = *(const float4*)(p + 4);
        } else {
            v0 = make_float4(0.f, 0.f, 0.f, 0.f);
            v1 = v0;
        }
        As[lk + 0][lr] = v0.x; As[lk + 1][lr] = v0.y; As[lk + 2][lr] = v0.z; As[lk + 3][lr] = v0.w;
        As[lk + 4][lr] = v1.x; As[lk + 5][lr] = v1.y; As[lk + 6][lr] = v1.z; As[lk + 7][lr] = v1.w;

        float4 w0 = *(const float4*)(W2 + (size_t)(kc + wk) * OC + col0 + wj);
        *(float4*)&Bs[wk][wj] = w0;
        __syncthreads();

        #pragma unroll
        for (int kk = 0; kk < 16; kk++) {
            float a[8], b[4];
            *(float4*)&a[0] = *(const float4*)&As[kk][ty * 8];
            *(float4*)&a[4] = *(const float4*)&As[kk][ty * 8 + 4];
            *(float4*)&b[0] = *(const float4*)&Bs[kk][tx * 4];
            #pragma unroll
            for (int i = 0; i < 8; i++)
                #pragma unroll
                for (int j = 0; j < 4; j++) acc[i][j] += a[i] * b[j];
        }
        __syncthreads();
    }

    #pragma unroll
    for (int i = 0; i < 8; i++) {
        int row = row0 + ty * 8 + i;
        if (row < n) {
            st_half4(h2h + (size_t)row * OC + col0 + tx * 4,
                     acc[i][0], acc[i][1], acc[i][2], acc[i][3]);
        }
    }
}

// ---------------- attention scores: a_s4 [N,4], a_d4 [N,4] (padded) ----------------
__global__ __launch_bounds__(256) void k_att(const __half* __restrict__ h2h, const float* __restrict__ att_s,
                                             const float* __restrict__ att_d, float* __restrict__ a_s4,
                                             float* __restrict__ a_d4, int n) {
    int w = (blockIdx.x * 256 + threadIdx.x) >> 6;
    int lane = threadIdx.x & 63;
    if (w >= n) return;
    #pragma unroll
    for (int hd = 0; hd < HEADS; hd++) {
        float hv = __half2float(h2h[(size_t)w * OC + hd * HC + lane]);
        float vs = hv * att_s[hd * HC + lane];
        float vd = hv * att_d[hd * HC + lane];
        #pragma unroll
        for (int o = 32; o > 0; o >>= 1) {
            vs += __shfl_xor(vs, o, 64);
            vd += __shfl_xor(vd, o, 64);
        }
        if (lane == 0) {
            a_s4[w * 4 + hd] = vs;
            a_d4[w * 4 + hd] = vd;
        }
    }
    if (lane == 0) { a_s4[w * 4 + 3] = 0.f; a_d4[w * 4 + 3] = 0.f; }
}

// ---------------- global per-head max of a_s (single block) ----------------
__global__ __launch_bounds__(1024) void k_asmax(const float* __restrict__ a_s4, int n, float* __restrict__ asmax) {
    float m0 = -1e30f, m1 = -1e30f, m2 = -1e30f;
    for (int i = threadIdx.x; i < n; i += 1024) {
        float4 v = *(const float4*)(a_s4 + (size_t)i * 4);
        m0 = fmaxf(m0, v.x); m1 = fmaxf(m1, v.y); m2 = fmaxf(m2, v.z);
    }
    #pragma unroll
    for (int o = 32; o > 0; o >>= 1) {
        m0 = fmaxf(m0, __shfl_xor(m0, o, 64));
        m1 = fmaxf(m1, __shfl_xor(m1, o, 64));
        m2 = fmaxf(m2, __shfl_xor(m2, o, 64));
    }
    __shared__ float sm[16][3];
    int lane = threadIdx.x & 63, wid = threadIdx.x >> 6;
    if (lane == 0) { sm[wid][0] = m0; sm[wid][1] = m1; sm[wid][2] = m2; }
    __syncthreads();
    if (threadIdx.x == 0) {
        for (int j = 1; j < 16; j++) {
            m0 = fmaxf(m0, sm[j][0]); m1 = fmaxf(m1, sm[j][1]); m2 = fmaxf(m2, sm[j][2]);
        }
        asmax[0] = m0; asmax[1] = m1; asmax[2] = m2;
    }
}

// ---------------- edge-parallel softmax weights ----------------
// w_h = exp(lrelu(a_s[s]+a_d[d]) - C_d,h), C_d,h = lrelu(asmax_h + a_d[d]) >= any score at d
__global__ __launch_bounds__(256) void k_edgew(const int* __restrict__ csr, const int* __restrict__ dstv,
                                               const float* __restrict__ a_s4, const float* __restrict__ a_d4,
                                               const float* __restrict__ asmax, int E, float* __restrict__ w4) {
    int p = blockIdx.x * 256 + threadIdx.x;
    if (p >= E) return;
    int s = csr[p], d = dstv[p];
    float4 as = *(const float4*)(a_s4 + (size_t)s * 4);
    float4 ad = *(const float4*)(a_d4 + (size_t)d * 4);
    float m0 = asmax[0], m1 = asmax[1], m2 = asmax[2];
    float4 wv;
    wv.x = __expf(lrelu(as.x + ad.x) - lrelu(m0 + ad.x));
    wv.y = __expf(lrelu(as.y + ad.y) - lrelu(m1 + ad.y));
    wv.z = __expf(lrelu(as.z + ad.z) - lrelu(m2 + ad.z));
    wv.w = 0.f;
    *(float4*)(w4 + (size_t)p * 4) = wv;
}

// ---------------- GAT aggregate: wave/node, precomputed weights, half4 lanes ----------------
// lane l<48 covers cols 4l..4l+3 (head = l/16); lanes 48-63 mirror head0 (stores masked).
__global__ __launch_bounds__(256) void k_gat(const __half* __restrict__ h2h, const int* __restrict__ csr,
                                             const int* __restrict__ off, const float* __restrict__ w4,
                                             const float* __restrict__ a_s4, const float* __restrict__ a_d4,
                                             const float* __restrict__ asmax, const float* __restrict__ b2,
                                             float* __restrict__ out, int n) {
    int w = (blockIdx.x * 256 + threadIdx.x) >> 6;
    int lane = threadIdx.x & 63;
    if (w >= n) return;
    bool g1 = lane >= 16, g2 = lane >= 32;
    bool act = lane < 48;
    int ll = act ? lane : (lane - 48);
    int c4 = ll * 4;

    // self-loop weight
    float4 asw = *(const float4*)(a_s4 + (size_t)w * 4);
    float4 adw = *(const float4*)(a_d4 + (size_t)w * 4);
    float ws0 = __expf(lrelu(asw.x + adw.x) - lrelu(asmax[0] + adw.x));
    float ws1 = __expf(lrelu(asw.y + adw.y) - lrelu(asmax[1] + adw.y));
    float ws2 = __expf(lrelu(asw.z + adw.z) - lrelu(asmax[2] + adw.z));
    float wsl = g2 ? ws2 : (g1 ? ws1 : ws0);
    float ssum = wsl;
    float4 hv = ld_half4(h2h + (size_t)w * OC + c4);
    float a0 = wsl * hv.x, a1 = wsl * hv.y, a2 = wsl * hv.z, a3 = wsl * hv.w;

    int beg = off[w], end = off[w + 1];
    int i = beg;
    for (; i + 4 <= end; i += 4) {
        int sA = csr[i], sB = csr[i + 1], sC = csr[i + 2], sD = csr[i + 3];
        float4 wA = *(const float4*)(w4 + (size_t)(i + 0) * 4);
        float4 wB = *(const float4*)(w4 + (size_t)(i + 1) * 4);
        float4 wC = *(const float4*)(w4 + (size_t)(i + 2) * 4);
        float4 wD = *(const float4*)(w4 + (size_t)(i + 3) * 4);
        float4 hA = ld_half4(h2h + (size_t)sA * OC + c4);
        float4 hB = ld_half4(h2h + (size_t)sB * OC + c4);
        float4 hC = ld_half4(h2h + (size_t)sC * OC + c4);
        float4 hD = ld_half4(h2h + (size_t)sD * OC + c4);
        float wlA = g2 ? wA.z : (g1 ? wA.y : wA.x);
        float wlB = g2 ? wB.z : (g1 ? wB.y : wB.x);
        float wlC = g2 ? wC.z : (g1 ? wC.y : wC.x);
        float wlD = g2 ? wD.z : (g1 ? wD.y : wD.x);
        ssum += wlA + wlB + wlC + wlD;
        a0 = fmaf(wlA, hA.x, a0); a1 = fmaf(wlA, hA.y, a1); a2 = fmaf(wlA, hA.z, a2); a3 = fmaf(wlA, hA.w, a3);
        a0 = fmaf(wlB, hB.x, a0); a1 = fmaf(wlB, hB.y, a1); a2 = fmaf(wlB, hB.z, a2); a3 = fmaf(wlB, hB.w, a3);
        a0 = fmaf(wlC, hC.x, a0); a1 = fmaf(wlC, hC.y, a1); a2 = fmaf(wlC, hC.z, a2); a3 = fmaf(wlC, hC.w, a3);
        a0 = fmaf(wlD, hD.x, a0); a1 = fmaf(wlD, hD.y, a1); a2 = fmaf(wlD, hD.z, a2); a3 = fmaf(wlD, hD.w, a3);
    }
    for (; i < end; i++) {
        int s = csr[i];
        float4 wv = *(const float4*)(w4 + (size_t)i * 4);
        float4 hv2 = ld_half4(h2h + (size_t)s * OC + c4);
        float wl = g2 ? wv.z : (g1 ? wv.y : wv.x);
        ssum += wl;
        a0 = fmaf(wl, hv2.x, a0); a1 = fmaf(wl, hv2.y, a1); a2 = fmaf(wl, hv2.z, a2); a3 = fmaf(wl, hv2.w, a3);
    }

    if (act) {
        float inv = 1.f / ssum;
        float4 bb = *(const float4*)(b2 + c4);
        float4 o;
        o.x = fmaxf(fmaf(a0, inv, bb.x), 0.f);
        o.y = fmaxf(fmaf(a1, inv, bb.y), 0.f);
        o.z = fmaxf(fmaf(a2, inv, bb.z), 0.f);
        o.w = fmaxf(fmaf(a3, inv, bb.w), 0.f);
        *(float4*)(out + (size_t)w * OC + c4) = o;
    }
}

// ---------------- launcher ----------------
extern "C" void kernel_launch(void* const* d_in, const int* in_sizes, int n_in,
                              void* d_out, int out_size, void* d_ws, size_t ws_size,
                              hipStream_t stream) {
    const float* x        = (const float*)d_in[0];
    const int*   ei       = (const int*)d_in[1];
    const float* W1       = (const float*)d_in[2];
    const float* b1       = (const float*)d_in[3];
    const float* W2       = (const float*)d_in[4];
    const float* att_src  = (const float*)d_in[5];
    const float* att_dst  = (const float*)d_in[6];
    const float* b2       = (const float*)d_in[7];
    float* out = (float*)d_out;

    const int n = in_sizes[0] / IN_CH;     // 50000
    const int E = in_sizes[1] / 2;         // 800000
    const int* src = ei;
    const int* dst = ei + E;

    // workspace layout (bytes), 256-aligned
    char* ws = (char*)d_ws;
    int*    cnt   = (int*)(ws + 0);               // 50000 i
    int*    fill  = (int*)(ws + 200704);          // 50000 i
    int*    off   = (int*)(ws + 401408);          // 50001 i
    float*  dinv  = (float*)(ws + 602112);        // 50000 f
    int*    bsum  = (int*)(ws + 802816);          // 49 i
    int*    bbase = (int*)(ws + 803072);          // 64 i
    float*  asmax = (float*)(ws + 803328);        // 3 f
    int*    csr   = (int*)(ws + 803584);          // 800000 i
    int*    dstv  = (int*)(ws + 4003840);         // 800000 i
    float*  a_s4  = (float*)(ws + 7203840);       // 50000*4 f
    float*  a_d4  = (float*)(ws + 8003840);       // 50000*4 f
    __half* xwh   = (__half*)(ws + 8803840);      // 50000*128 h (pre-scaled by dinv)
    float*  w4    = (float*)(ws + 8803840);       // 800000*4 f -- ALIASES xwh (dead after k_gcn)
    float*  h     = (float*)(ws + 21603840);      // 50000*128 f
    __half* h2h   = (__half*)(ws + 47203840);     // 50000*192 h
    // total ~66.5 MB

    hipMemsetAsync(ws, 0, 401408, stream);        // cnt + fill

    int egrid = (E + 255) / 256;
    int nb = (n + 1023) / 1024;                   // 49
    k_hist<<<egrid, 256, 0, stream>>>(dst, E, cnt);
    k_scanA<<<nb, 1024, 0, stream>>>(cnt, off, dinv, bsum, n);
    k_scanB<<<1, 64, 0, stream>>>(bsum, bbase, off, nb, n);
    k_scanC<<<(n + 255) / 256, 256, 0, stream>>>(off, bbase, n);
    k_fill<<<egrid, 256, 0, stream>>>(src, dst, E, off, fill, csr, dstv);

    int g1 = (n + 127) / 128;
    k_gemm1<<<g1, 256, 0, stream>>>(x, W1, dinv, xwh, n);

    int ngrid = (n + 3) / 4;   // 4 waves per block
    k_gcn<<<ngrid, 256, 0, stream>>>(xwh, csr, off, dinv, b1, h, n);

    dim3 g2((n + 127) / 128, 3);
    k_gemm2<<<g2, 256, 0, stream>>>(h, W2, h2h, n);

    k_att<<<ngrid, 256, 0, stream>>>(h2h, att_src, att_dst, a_s4, a_d4, n);
    k_asmax<<<1, 1024, 0, stream>>>(a_s4, n, asmax);
    k_edgew<<<egrid, 256, 0, stream>>>(csr, dstv, a_s4, a_d4, asmax, E, w4);
    k_gat<<<ngrid, 256, 0, stream>>>(h2h, csr, off, w4, a_s4, a_d4, asmax, b2, out, n);
}

// Round 6
// 327.193 us; speedup vs baseline: 1.6261x; 1.0493x over previous
//
#include <hip/hip_runtime.h>
#include <hip/hip_fp16.h>
#include <math.h>

// Problem constants (verified against reference setup_inputs)
#define NODES    50000
#define IN_CH    256
#define HID      128
#define HEADS    3
#define HC       64
#define OC       (HEADS*HC)   // 192
#define NEG_SLOPE 0.2f

typedef _Float16 half8_t __attribute__((ext_vector_type(8)));
typedef float float4_t __attribute__((ext_vector_type(4)));

__device__ __forceinline__ float lrelu(float v) { return v > 0.f ? v : NEG_SLOPE * v; }

// ---- fp16 pack helpers ----
__device__ __forceinline__ float4 ld_half4(const _Float16* p) {
    float2 raw = *(const float2*)p;                       // one 8B load
    const __half2* h = reinterpret_cast<const __half2*>(&raw);
    float2 a = __half22float2(h[0]);
    float2 b = __half22float2(h[1]);
    return make_float4(a.x, a.y, b.x, b.y);
}
__device__ __forceinline__ void st_half4(_Float16* p, float x, float y, float z, float w) {
    __half2 h0 = __floats2half2_rn(x, y);
    __half2 h1 = __floats2half2_rn(z, w);
    float2 raw;
    raw.x = *reinterpret_cast<float*>(&h0);
    raw.y = *reinterpret_cast<float*>(&h1);
    *(float2*)p = raw;                                    // one 8B store
}

// ---------------- CSR build ----------------

__global__ __launch_bounds__(256) void k_hist(const int* __restrict__ dst, int E, int* __restrict__ cnt) {
    int e = blockIdx.x * 256 + threadIdx.x;
    if (e < E) atomicAdd(&cnt[dst[e]], 1);
}

__global__ __launch_bounds__(1024) void k_scanA(const int* __restrict__ cnt, int* __restrict__ off,
                                                float* __restrict__ dinv, int* __restrict__ bsum, int n) {
    __shared__ int wsums[16];
    int tid = threadIdx.x, lane = tid & 63, wid = tid >> 6;
    int i = blockIdx.x * 1024 + tid;
    int v = (i < n) ? cnt[i] : 0;
    int incl = v;
    #pragma unroll
    for (int d = 1; d < 64; d <<= 1) {
        int t = __shfl_up(incl, d, 64);
        if (lane >= d) incl += t;
    }
    if (lane == 63) wsums[wid] = incl;
    __syncthreads();
    if (tid == 0) {
        int run = 0;
        #pragma unroll
        for (int j = 0; j < 16; j++) { int t = wsums[j]; wsums[j] = run; run += t; }
        bsum[blockIdx.x] = run;
    }
    __syncthreads();
    if (i < n) {
        off[i] = wsums[wid] + incl - v;
        dinv[i] = rsqrtf((float)(v + 1));   // +1 for self loop
    }
}

__global__ __launch_bounds__(64) void k_scanB(const int* __restrict__ bsum, int* __restrict__ bbase,
                                              int* __restrict__ off, int nb, int n) {
    int tid = threadIdx.x;
    int v = (tid < nb) ? bsum[tid] : 0;
    int incl = v;
    #pragma unroll
    for (int d = 1; d < 64; d <<= 1) {
        int t = __shfl_up(incl, d, 64);
        if (tid >= d) incl += t;
    }
    bbase[tid] = incl - v;
    if (tid == 63) off[n] = incl;   // grand total = E
}

__global__ __launch_bounds__(256) void k_scanC(int* __restrict__ off, const int* __restrict__ bbase, int n) {
    int i = blockIdx.x * 256 + threadIdx.x;
    if (i < n) off[i] += bbase[i >> 10];
}

// csr only (dstv eliminated -> one scattered 4B write per edge instead of two)
__global__ __launch_bounds__(256) void k_fill(const int* __restrict__ src, const int* __restrict__ dst, int E,
                                              const int* __restrict__ off, int* __restrict__ fill,
                                              int* __restrict__ csr) {
    int e = blockIdx.x * 256 + threadIdx.x;
    if (e < E) {
        int d = dst[e];
        int p = off[d] + atomicAdd(&fill[d], 1);
        csr[p] = src[e];
    }
}

// ---------------- weight transpose+fp16 prepass: Wt[c][k] = (fp16)W[k][c] ----------------
__global__ __launch_bounds__(256) void k_cvtW(const float* __restrict__ W, _Float16* __restrict__ Wt,
                                              int kshift, int N, int total) {
    int t = blockIdx.x * 256 + threadIdx.x;
    if (t < total) {
        int K = 1 << kshift;
        int c = t >> kshift, k = t & (K - 1);
        Wt[t] = (_Float16)W[(size_t)k * N + c];
    }
}

// ---------------- GEMM1 (MFMA): xwh = fp16( dinv[row] * (x @ W1) ) ----------------
// 4 waves/block, wave owns 16 rows; N=128 = 8 subtiles of 16; K=256 in 8 steps of 32.
// No LDS: A-frags straight from global x (fp32->fp16 cvt), B-frags from W1t (L2-hot 64KB).
__global__ __launch_bounds__(256) void k_gemm1m(const float* __restrict__ x, const _Float16* __restrict__ W1t,
                                                const float* __restrict__ dinv,
                                                _Float16* __restrict__ xwh, int n) {
    int wid = threadIdx.x >> 6, lane = threadIdx.x & 63;
    int lrow = lane & 15, kgrp = lane >> 4;          // A: row=lrow, k-chunk=kgrp*8
    int arow = blockIdx.x * 64 + wid * 16 + lrow;
    bool rv = arow < n;
    const float* xp = x + (size_t)arow * IN_CH + kgrp * 8;

    float4_t acc[8];
    #pragma unroll
    for (int s = 0; s < 8; s++) acc[s] = (float4_t)(0.f);

    #pragma unroll
    for (int kc = 0; kc < IN_CH; kc += 32) {
        float4 a0, a1;
        if (rv) { a0 = *(const float4*)(xp + kc); a1 = *(const float4*)(xp + kc + 4); }
        else { a0 = make_float4(0.f,0.f,0.f,0.f); a1 = a0; }
        half8_t af;
        af[0]=(_Float16)a0.x; af[1]=(_Float16)a0.y; af[2]=(_Float16)a0.z; af[3]=(_Float16)a0.w;
        af[4]=(_Float16)a1.x; af[5]=(_Float16)a1.y; af[6]=(_Float16)a1.z; af[7]=(_Float16)a1.w;
        #pragma unroll
        for (int s = 0; s < 8; s++) {
            const _Float16* bp = W1t + (size_t)(s * 16 + lrow) * IN_CH + kc + kgrp * 8;
            half8_t bf = *(const half8_t*)bp;
            acc[s] = __builtin_amdgcn_mfma_f32_16x16x32_f16(af, bf, acc[s], 0, 0, 0);
        }
    }

    // C/D: col = lane&15 (=lrow), row = kgrp*4 + r
    int orow0 = blockIdx.x * 64 + wid * 16 + kgrp * 4;
    #pragma unroll
    for (int r = 0; r < 4; r++) {
        int orow = orow0 + r;
        if (orow < n) {
            float sc = dinv[orow];
            _Float16* po = xwh + (size_t)orow * HID + lrow;
            #pragma unroll
            for (int s = 0; s < 8; s++) po[s * 16] = (_Float16)(sc * acc[s][r]);
        }
    }
}

// ---------------- GCN aggregate: wave/node, pair-edge half4 lanes; fp16 output ----------------
__global__ __launch_bounds__(256) void k_gcn(const _Float16* __restrict__ xwh, const int* __restrict__ csr,
                                             const int* __restrict__ off, const float* __restrict__ dinv,
                                             const float* __restrict__ b1, _Float16* __restrict__ hh, int n) {
    int w = (blockIdx.x * 256 + threadIdx.x) >> 6;
    int lane = threadIdx.x & 63;
    if (w >= n) return;
    int half = lane >> 5;
    int c4 = (lane & 31) * 4;
    float di = dinv[w];
    float a0 = 0.f, a1 = 0.f, a2 = 0.f, a3 = 0.f;
    int beg = off[w], end = off[w + 1];
    int i = beg;
    for (; i + 8 <= end; i += 8) {
        int s0 = csr[i + half];
        int s1 = csr[i + 2 + half];
        int s2 = csr[i + 4 + half];
        int s3 = csr[i + 6 + half];
        float4 v0 = ld_half4(xwh + (size_t)s0 * HID + c4);
        float4 v1 = ld_half4(xwh + (size_t)s1 * HID + c4);
        float4 v2 = ld_half4(xwh + (size_t)s2 * HID + c4);
        float4 v3 = ld_half4(xwh + (size_t)s3 * HID + c4);
        a0 += v0.x + v1.x + v2.x + v3.x;
        a1 += v0.y + v1.y + v2.y + v3.y;
        a2 += v0.z + v1.z + v2.z + v3.z;
        a3 += v0.w + v1.w + v2.w + v3.w;
    }
    for (; i + 2 <= end; i += 2) {
        int s = csr[i + half];
        float4 v = ld_half4(xwh + (size_t)s * HID + c4);
        a0 += v.x; a1 += v.y; a2 += v.z; a3 += v.w;
    }
    if (i < end && half == 0) {
        int s = csr[i];
        float4 v = ld_half4(xwh + (size_t)s * HID + c4);
        a0 += v.x; a1 += v.y; a2 += v.z; a3 += v.w;
    }
    a0 += __shfl_xor(a0, 32, 64);
    a1 += __shfl_xor(a1, 32, 64);
    a2 += __shfl_xor(a2, 32, 64);
    a3 += __shfl_xor(a3, 32, 64);
    if (half == 0) {
        float4 vs = ld_half4(xwh + (size_t)w * HID + c4);   // self (pre-scaled)
        float4 bb = *(const float4*)(b1 + c4);
        st_half4(hh + (size_t)w * HID + c4,
                 fmaxf(fmaf(di, a0 + vs.x, bb.x), 0.f),
                 fmaxf(fmaf(di, a1 + vs.y, bb.y), 0.f),
                 fmaxf(fmaf(di, a2 + vs.z, bb.z), 0.f),
                 fmaxf(fmaf(di, a3 + vs.w, bb.w), 0.f));
    }
}

// ---------------- GEMM2 (MFMA): h2h = fp16( h @ W2 )  [N,128]x[128,192] ----------------
// 4 waves/block, wave owns 16 rows; N=192 = 12 subtiles; K=128 in 4 steps of 32.
__global__ __launch_bounds__(256) void k_gemm2m(const _Float16* __restrict__ hh, const _Float16* __restrict__ W2t,
                                                _Float16* __restrict__ h2h, int n) {
    int wid = threadIdx.x >> 6, lane = threadIdx.x & 63;
    int lrow = lane & 15, kgrp = lane >> 4;
    int arow = blockIdx.x * 64 + wid * 16 + lrow;
    bool rv = arow < n;
    const _Float16* hp = hh + (size_t)arow * HID + kgrp * 8;

    float4_t acc[12];
    #pragma unroll
    for (int s = 0; s < 12; s++) acc[s] = (float4_t)(0.f);

    #pragma unroll
    for (int kc = 0; kc < HID; kc += 32) {
        half8_t af = (half8_t)((_Float16)0.f);
        if (rv) af = *(const half8_t*)(hp + kc);
        #pragma unroll
        for (int s = 0; s < 12; s++) {
            const _Float16* bp = W2t + (size_t)(s * 16 + lrow) * HID + kc + kgrp * 8;
            half8_t bf = *(const half8_t*)bp;
            acc[s] = __builtin_amdgcn_mfma_f32_16x16x32_f16(af, bf, acc[s], 0, 0, 0);
        }
    }

    int orow0 = blockIdx.x * 64 + wid * 16 + kgrp * 4;
    #pragma unroll
    for (int r = 0; r < 4; r++) {
        int orow = orow0 + r;
        if (orow < n) {
            _Float16* po = h2h + (size_t)orow * OC + lrow;
            #pragma unroll
            for (int s = 0; s < 12; s++) po[s * 16] = (_Float16)acc[s][r];
        }
    }
}

// ---------------- attention scores: a_s4 [N,4], a_d4 [N,4] (padded) ----------------
__global__ __launch_bounds__(256) void k_att(const _Float16* __restrict__ h2h, const float* __restrict__ att_s,
                                             const float* __restrict__ att_d, float* __restrict__ a_s4,
                                             float* __restrict__ a_d4, int n) {
    int w = (blockIdx.x * 256 + threadIdx.x) >> 6;
    int lane = threadIdx.x & 63;
    if (w >= n) return;
    #pragma unroll
    for (int hd = 0; hd < HEADS; hd++) {
        float hv = (float)h2h[(size_t)w * OC + hd * HC + lane];
        float vs = hv * att_s[hd * HC + lane];
        float vd = hv * att_d[hd * HC + lane];
        #pragma unroll
        for (int o = 32; o > 0; o >>= 1) {
            vs += __shfl_xor(vs, o, 64);
            vd += __shfl_xor(vd, o, 64);
        }
        if (lane == 0) {
            a_s4[w * 4 + hd] = vs;
            a_d4[w * 4 + hd] = vd;
        }
    }
    if (lane == 0) { a_s4[w * 4 + 3] = 0.f; a_d4[w * 4 + 3] = 0.f; }
}

// ---------------- global per-head max of a_s (single block) ----------------
__global__ __launch_bounds__(1024) void k_asmax(const float* __restrict__ a_s4, int n, float* __restrict__ asmax) {
    float m0 = -1e30f, m1 = -1e30f, m2 = -1e30f;
    for (int i = threadIdx.x; i < n; i += 1024) {
        float4 v = *(const float4*)(a_s4 + (size_t)i * 4);
        m0 = fmaxf(m0, v.x); m1 = fmaxf(m1, v.y); m2 = fmaxf(m2, v.z);
    }
    #pragma unroll
    for (int o = 32; o > 0; o >>= 1) {
        m0 = fmaxf(m0, __shfl_xor(m0, o, 64));
        m1 = fmaxf(m1, __shfl_xor(m1, o, 64));
        m2 = fmaxf(m2, __shfl_xor(m2, o, 64));
    }
    __shared__ float sm[16][3];
    int lane = threadIdx.x & 63, wid = threadIdx.x >> 6;
    if (lane == 0) { sm[wid][0] = m0; sm[wid][1] = m1; sm[wid][2] = m2; }
    __syncthreads();
    if (threadIdx.x == 0) {
        for (int j = 1; j < 16; j++) {
            m0 = fmaxf(m0, sm[j][0]); m1 = fmaxf(m1, sm[j][1]); m2 = fmaxf(m2, sm[j][2]);
        }
        asmax[0] = m0; asmax[1] = m1; asmax[2] = m2;
    }
}

// ---------------- edge softmax weights: wave per dst node (a_d, C_d wave-uniform) ----------------
__global__ __launch_bounds__(256) void k_edgew(const int* __restrict__ csr, const int* __restrict__ off,
                                               const float* __restrict__ a_s4, const float* __restrict__ a_d4,
                                               const float* __restrict__ asmax, float* __restrict__ w4, int n) {
    int w = (blockIdx.x * 256 + threadIdx.x) >> 6;
    int lane = threadIdx.x & 63;
    if (w >= n) return;
    float4 ad = *(const float4*)(a_d4 + (size_t)w * 4);
    float C0 = lrelu(asmax[0] + ad.x);
    float C1 = lrelu(asmax[1] + ad.y);
    float C2 = lrelu(asmax[2] + ad.z);
    int beg = off[w], end = off[w + 1];
    for (int i = beg + lane; i < end; i += 64) {
        int s = csr[i];
        float4 as = *(const float4*)(a_s4 + (size_t)s * 4);
        float4 wv;
        wv.x = __expf(lrelu(as.x + ad.x) - C0);
        wv.y = __expf(lrelu(as.y + ad.y) - C1);
        wv.z = __expf(lrelu(as.z + ad.z) - C2);
        wv.w = 0.f;
        *(float4*)(w4 + (size_t)i * 4) = wv;
    }
}

// ---------------- GAT aggregate: wave/node, precomputed weights, half4 lanes, unroll-8 ----------------
#define GAT_EDGE(wv, hv) do { \
    float wl = g2 ? (wv).z : (g1 ? (wv).y : (wv).x); \
    ssum += wl; \
    a0 = fmaf(wl, (hv).x, a0); a1 = fmaf(wl, (hv).y, a1); \
    a2 = fmaf(wl, (hv).z, a2); a3 = fmaf(wl, (hv).w, a3); \
} while (0)

__global__ __launch_bounds__(256) void k_gat(const _Float16* __restrict__ h2h, const int* __restrict__ csr,
                                             const int* __restrict__ off, const float* __restrict__ w4,
                                             const float* __restrict__ a_s4, const float* __restrict__ a_d4,
                                             const float* __restrict__ asmax, const float* __restrict__ b2,
                                             float* __restrict__ out, int n) {
    int w = (blockIdx.x * 256 + threadIdx.x) >> 6;
    int lane = threadIdx.x & 63;
    if (w >= n) return;
    bool g1 = lane >= 16, g2 = lane >= 32;
    bool act = lane < 48;
    int ll = act ? lane : (lane - 48);
    int c4 = ll * 4;

    // self-loop weight
    float4 asw = *(const float4*)(a_s4 + (size_t)w * 4);
    float4 adw = *(const float4*)(a_d4 + (size_t)w * 4);
    float ws0 = __expf(lrelu(asw.x + adw.x) - lrelu(asmax[0] + adw.x));
    float ws1 = __expf(lrelu(asw.y + adw.y) - lrelu(asmax[1] + adw.y));
    float ws2 = __expf(lrelu(asw.z + adw.z) - lrelu(asmax[2] + adw.z));
    float wsl = g2 ? ws2 : (g1 ? ws1 : ws0);
    float ssum = wsl;
    float4 hv = ld_half4(h2h + (size_t)w * OC + c4);
    float a0 = wsl * hv.x, a1 = wsl * hv.y, a2 = wsl * hv.z, a3 = wsl * hv.w;

    int beg = off[w], end = off[w + 1];
    int i = beg;
    for (; i + 8 <= end; i += 8) {
        int sA = csr[i],     sB = csr[i + 1], sC = csr[i + 2], sD = csr[i + 3];
        int sE = csr[i + 4], sF = csr[i + 5], sG = csr[i + 6], sH = csr[i + 7];
        float4 wA = *(const float4*)(w4 + (size_t)(i + 0) * 4);
        float4 wB = *(const float4*)(w4 + (size_t)(i + 1) * 4);
        float4 wC = *(const float4*)(w4 + (size_t)(i + 2) * 4);
        float4 wD = *(const float4*)(w4 + (size_t)(i + 3) * 4);
        float4 wE = *(const float4*)(w4 + (size_t)(i + 4) * 4);
        float4 wF = *(const float4*)(w4 + (size_t)(i + 5) * 4);
        float4 wG = *(const float4*)(w4 + (size_t)(i + 6) * 4);
        float4 wH = *(const float4*)(w4 + (size_t)(i + 7) * 4);
        float4 hA = ld_half4(h2h + (size_t)sA * OC + c4);
        float4 hB = ld_half4(h2h + (size_t)sB * OC + c4);
        float4 hC = ld_half4(h2h + (size_t)sC * OC + c4);
        float4 hD = ld_half4(h2h + (size_t)sD * OC + c4);
        float4 hE = ld_half4(h2h + (size_t)sE * OC + c4);
        float4 hF = ld_half4(h2h + (size_t)sF * OC + c4);
        float4 hG = ld_half4(h2h + (size_t)sG * OC + c4);
        float4 hH = ld_half4(h2h + (size_t)sH * OC + c4);
        GAT_EDGE(wA, hA); GAT_EDGE(wB, hB); GAT_EDGE(wC, hC); GAT_EDGE(wD, hD);
        GAT_EDGE(wE, hE); GAT_EDGE(wF, hF); GAT_EDGE(wG, hG); GAT_EDGE(wH, hH);
    }
    for (; i < end; i++) {
        int s = csr[i];
        float4 wv = *(const float4*)(w4 + (size_t)i * 4);
        float4 hx = ld_half4(h2h + (size_t)s * OC + c4);
        GAT_EDGE(wv, hx);
    }

    if (act) {
        float inv = 1.f / ssum;
        float4 bb = *(const float4*)(b2 + c4);
        float4 o;
        o.x = fmaxf(fmaf(a0, inv, bb.x), 0.f);
        o.y = fmaxf(fmaf(a1, inv, bb.y), 0.f);
        o.z = fmaxf(fmaf(a2, inv, bb.z), 0.f);
        o.w = fmaxf(fmaf(a3, inv, bb.w), 0.f);
        *(float4*)(out + (size_t)w * OC + c4) = o;
    }
}

// ---------------- launcher ----------------
extern "C" void kernel_launch(void* const* d_in, const int* in_sizes, int n_in,
                              void* d_out, int out_size, void* d_ws, size_t ws_size,
                              hipStream_t stream) {
    const float* x        = (const float*)d_in[0];
    const int*   ei       = (const int*)d_in[1];
    const float* W1       = (const float*)d_in[2];
    const float* b1       = (const float*)d_in[3];
    const float* W2       = (const float*)d_in[4];
    const float* att_src  = (const float*)d_in[5];
    const float* att_dst  = (const float*)d_in[6];
    const float* b2       = (const float*)d_in[7];
    float* out = (float*)d_out;

    const int n = in_sizes[0] / IN_CH;     // 50000
    const int E = in_sizes[1] / 2;         // 800000
    const int* src = ei;
    const int* dst = ei + E;

    // workspace layout (bytes), 256-aligned
    char* ws = (char*)d_ws;
    int*      cnt   = (int*)(ws + 0);               // 50000 i
    int*      fill  = (int*)(ws + 200704);          // 50000 i
    int*      off   = (int*)(ws + 401408);          // 50001 i
    float*    dinv  = (float*)(ws + 602112);        // 50000 f
    int*      bsum  = (int*)(ws + 802816);          // 49 i
    int*      bbase = (int*)(ws + 803072);          // 64 i
    float*    asmax = (float*)(ws + 803328);        // 3 f
    _Float16* W1t   = (_Float16*)(ws + 803584);     // 128*256 h = 65536 B
    _Float16* W2t   = (_Float16*)(ws + 869120);     // 192*128 h = 49152 B
    int*      csr   = (int*)(ws + 918528);          // 800000 i
    float*    a_s4  = (float*)(ws + 4118528);       // 50000*4 f
    float*    a_d4  = (float*)(ws + 4918528);       // 50000*4 f
    _Float16* xwh   = (_Float16*)(ws + 5718528);    // 50000*128 h (pre-scaled by dinv)
    float*    w4    = (float*)(ws + 5718528);       // 800000*4 f -- ALIASES xwh (dead after k_gcn)
    _Float16* hh    = (_Float16*)(ws + 18518528);   // 50000*128 h
    _Float16* h2h   = (_Float16*)(ws + 31318528);   // 50000*192 h
    // total ~50.5 MB

    (void)hipMemsetAsync(ws, 0, 401408, stream);    // cnt + fill

    int egrid = (E + 255) / 256;
    int nb = (n + 1023) / 1024;                     // 49
    k_hist<<<egrid, 256, 0, stream>>>(dst, E, cnt);
    k_scanA<<<nb, 1024, 0, stream>>>(cnt, off, dinv, bsum, n);
    k_scanB<<<1, 64, 0, stream>>>(bsum, bbase, off, nb, n);
    k_scanC<<<(n + 255) / 256, 256, 0, stream>>>(off, bbase, n);
    k_fill<<<egrid, 256, 0, stream>>>(src, dst, E, off, fill, csr);

    k_cvtW<<<(IN_CH * HID + 255) / 256, 256, 0, stream>>>(W1, W1t, 8, HID, IN_CH * HID);
    k_cvtW<<<(HID * OC + 255) / 256, 256, 0, stream>>>(W2, W2t, 7, OC, HID * OC);

    int gm = (n + 63) / 64;    // 782 blocks, 4 waves each
    k_gemm1m<<<gm, 256, 0, stream>>>(x, W1t, dinv, xwh, n);

    int ngrid = (n + 3) / 4;   // 4 waves per block
    k_gcn<<<ngrid, 256, 0, stream>>>(xwh, csr, off, dinv, b1, hh, n);

    k_gemm2m<<<gm, 256, 0, stream>>>(hh, W2t, h2h, n);

    k_att<<<ngrid, 256, 0, stream>>>(h2h, att_src, att_dst, a_s4, a_d4, n);
    k_asmax<<<1, 1024, 0, stream>>>(a_s4, n, asmax);
    k_edgew<<<ngrid, 256, 0, stream>>>(csr, off, a_s4, a_d4, asmax, w4, n);
    k_gat<<<ngrid, 256, 0, stream>>>(h2h, csr, off, w4, a_s4, a_d4, asmax, b2, out, n);
}